// Round 8
// baseline (171.083 us; speedup 1.0000x reference)
//
#include <hip/hip_runtime.h>
#include <stdint.h>

#define NGK   5
#define NFK   10
#define NWK   8
#define STEPW 16      // NG + NF + 1
#define NSEQ  512
#define FDIM  32
#define NBAT  128
#define SROWS 576     // skewed rows: max real row = 511 + 63 = 574
#define RING  32      // dp LDS ring depth (rows); vmcnt stays < 63
#define BIGV  1000000000.0f

#define INVGL 0.28853900817779268f   // 1/(gamma*ln2)
#define GLN2  3.4657359027997265f    // gamma*ln2

#define EXP2F(x) __builtin_amdgcn_exp2f(x)
#define LOG2F(x) __builtin_amdgcn_logf(x)   // v_log_f32 = log2 (validated r1-r7)

typedef short bf16x8 __attribute__((ext_vector_type(8)));
typedef float f32x4  __attribute__((ext_vector_type(4)));
union U32F { uint32_t u; float f; };

__device__ __forceinline__ uint32_t f2bf(float f) {  // f32 -> bf16 RNE
    U32F c; c.f = f;
    return (c.u + 0x7FFFu + ((c.u >> 16) & 1u)) >> 16;
}
__device__ __forceinline__ float bflo(uint32_t u) { U32F c; c.u = u << 16; return c.f; }
__device__ __forceinline__ float bfhi(uint32_t u) { U32F c; c.u = u & 0xFFFF0000u; return c.f; }

// lane n <- lane n-1 (DPP wave_shr:1 = 0x138); lane 0 -> 0 (= E-domain boundary).
__device__ __forceinline__ float dpp_shr1_f(float v) {
    U32F c; c.f = v;
    c.u = (uint32_t)__builtin_amdgcn_update_dpp(0, (int)c.u, 0x138, 0xF, 0xF, true);
    return c.f;
}

// async global->LDS, 16 B per lane; LDS dest = wave-uniform base + lane*16.
__device__ __forceinline__ void gload_row(const uint16_t* gsrc_lane, uint32_t* lds_slot) {
    __builtin_amdgcn_global_load_lds(
        (const __attribute__((address_space(1))) uint32_t*)gsrc_lane,
        (__attribute__((address_space(3))) uint32_t*)lds_slot,
        16, 0, 0);
}

// ---------- kernel 0: stage x -> bf16 rows (64 B) + row norms ----------
__global__ __launch_bounds__(256, 1) void prep_kernel(
    const float* __restrict__ data, uint16_t* __restrict__ xbf,
    float* __restrict__ sq)
{
    __shared__ uint32_t LB[NSEQ * 16];   // 32 KB bf16-pair rows
    const int b = blockIdx.x;
    const int t = threadIdx.x;
    const float4* xb4 = (const float4*)(data + (size_t)b * (NSEQ * FDIM));
    uint2* xg = (uint2*)(xbf + (size_t)b * (NSEQ * FDIM));

    #pragma unroll
    for (int it = 0; it < 16; ++it) {
        int q = it * 256 + t;            // float4 index, 4096 total
        float4 v = xb4[q];
        uint32_t u0 = f2bf(v.x) | (f2bf(v.y) << 16);
        uint32_t u1 = f2bf(v.z) | (f2bf(v.w) << 16);
        LB[q * 2] = u0; LB[q * 2 + 1] = u1;
        uint2 st; st.x = u0; st.y = u1;
        xg[q] = st;
    }
    __syncthreads();
    #pragma unroll
    for (int rr = 0; rr < 2; ++rr) {
        int r = t + rr * 256;
        float acc = 0.f;
        #pragma unroll
        for (int c = 0; c < 16; ++c) {
            uint32_t u = LB[r * 16 + c];
            float lo = bflo(u), hi = bfhi(u);
            acc = fmaf(lo, lo, acc);
            acc = fmaf(hi, hi, acc);
        }
        sq[(size_t)b * NSEQ + r] = acc;
    }
}

// ---------- kernel 1: MFMA -> skewed bf16 W matrix (no staging; L2-hot reads) ----------
// Wsk[b][s][i] = 2^(-D[i][ s-(i>>3) ] * INVGL), 0 where i>=L or j>=L.
__global__ __launch_bounds__(256, 1) void dgen_kernel(
    const uint16_t* __restrict__ xbf, const float* __restrict__ sq,
    const int* __restrict__ lens, uint16_t* __restrict__ wsk)
{
    const int tj = blockIdx.x, b = blockIdx.y;
    int L = lens[b]; L = L < 1 ? 1 : (L > NSEQ ? NSEQ : L);
    const int smax = (L - 1) + ((L - 1) >> 3);
    int maxrow = smax + 8; if (maxrow > SROWS - 1) maxrow = SROWS - 1;
    if (tj * 16 > maxrow) return;

    const int t = threadIdx.x;
    const int w = t >> 6, lane = t & 63, rl = lane & 15, kq = lane >> 4, rr0 = kq * 4;
    const int j = tj * 16 + rl;

    const short* xb  = (const short*)(xbf + (size_t)b * (NSEQ * FDIM));
    const float* sqb = sq + (size_t)b * NSEQ;
    uint16_t* wb = wsk + (size_t)b * (SROWS * NSEQ);

    bf16x8 bfrag = *(const bf16x8*)(xb + j * FDIM + kq * 8);   // validated B-frag
    float sqJ = sqb[j];
    const bool jok = j < L;

    for (int it = 0; it < 8; ++it) {
        int ti = w * 8 + it;
        if (tj * 16 + ti * 2 > maxrow) break;      // wave-uniform
        bf16x8 afrag = *(const bf16x8*)(xb + (ti * 16 + rl) * FDIM + kq * 8);
        f32x4 c = {0.f, 0.f, 0.f, 0.f};
        c = __builtin_amdgcn_mfma_f32_16x16x32_bf16(afrag, bfrag, c, 0, 0, 0);
        f32x4 s4 = *(const f32x4*)(sqb + ti * 16 + rr0);
        float wv[4];
        #pragma unroll
        for (int q2 = 0; q2 < 4; ++q2) {
            int i = ti * 16 + rr0 + q2;
            float dv = s4[q2] + sqJ - 2.f * c[q2];
            float e = EXP2F(-INVGL * dv);
            wv[q2] = (jok && (i < L)) ? e : 0.f;
        }
        int sr = j + ti * 2 + (rr0 >> 3);          // skewed row
        uint2 st;
        st.x = f2bf(wv[0]) | (f2bf(wv[1]) << 16);
        st.y = f2bf(wv[2]) | (f2bf(wv[3]) << 16);
        *(uint2*)(wb + (size_t)sr * NSEQ + ti * 16 + rr0) = st;
    }
}

// ---------- kernel 2: exp-domain soft-DTW, one wave per batch ----------
// LDS ring (32 rows x 1 KB) fed by global_load_lds; explicit counted vmcnt keeps
// 32 rows in flight regardless of compiler scheduling. 4-deep named LDS->reg
// prefetch covers ds_read latency. E' = (E_diag + E_up + E_left) * W, 8-FMA chain.
__global__ __launch_bounds__(64, 1) void dp_kernel(
    const uint16_t* __restrict__ wsk, const int* __restrict__ lens,
    float* __restrict__ dists)
{
    __shared__ __align__(16) uint32_t WR[RING * 256];   // 32 KB ring, slot = 1 KB row

    const int b = blockIdx.x, wl = threadIdx.x;
    const uint16_t* wb = wsk + (size_t)b * (SROWS * NSEQ);
    int L = lens[b]; L = L < 1 ? 1 : (L > NSEQ ? NSEQ : L);
    const int lout = (L - 1) >> 3, qout = (L - 1) & 7, smax = (L - 1) + lout;

    // prologue: fill the ring (rows 0..31; issue order == row order)
    #pragma unroll
    for (int r = 0; r < RING; ++r) {
        gload_row(wb + (size_t)r * NSEQ + wl * 8, &WR[r * 256]);
    }
    asm volatile("s_waitcnt vmcnt(28)" ::: "memory");   // rows 0..3 landed
    __builtin_amdgcn_sched_barrier(0);
    uint4 q0 = *(const uint4*)&WR[0 * 256 + wl * 4];
    uint4 q1 = *(const uint4*)&WR[1 * 256 + wl * 4];
    uint4 q2 = *(const uint4*)&WR[2 * 256 + wl * 4];
    uint4 q3 = *(const uint4*)&WR[3 * 256 + wl * 4];

    float E0 = 0.f, E1 = 0.f, E2 = 0.f, E3 = 0.f,
          E4 = 0.f, E5 = 0.f, E6 = 0.f, E7 = 0.f;
    float ap = (wl == 0) ? 1.0f : 0.f;   // virtual start: diag pred of (0,0) = exp(0)

    int s = 0;

#define PHASE(Q) {                                                            \
    /* extract W for row s (lgkmcnt for the 4-step-old ds_read, compiler) */  \
    float w0 = bflo(Q.x), w1 = bfhi(Q.x), w2 = bflo(Q.y), w3 = bfhi(Q.y);     \
    float w4 = bflo(Q.z), w5 = bfhi(Q.z), w6 = bflo(Q.w), w7 = bfhi(Q.w);     \
    /* issue DMA for row s+RING into slot s&31 (slot's reader finished) */    \
    int gl = s + RING; if (gl > SROWS - 1) gl = SROWS - 1;                    \
    gload_row(wb + (size_t)gl * NSEQ + wl * 8, &WR[(s & (RING - 1)) * 256]);  \
    /* row s+4 is landed once <=28 loads outstanding (issued = s+33) */       \
    asm volatile("s_waitcnt vmcnt(28)" ::: "memory");                         \
    __builtin_amdgcn_sched_barrier(0);                                        \
    Q = *(const uint4*)&WR[((s + 4) & (RING - 1)) * 256 + wl * 4];            \
    /* DP step */                                                             \
    float bu = dpp_shr1_f(E7);                                                \
    float A0 = (ap + E0) * w0, A1 = (E0 + E1) * w1;                           \
    float A2 = (E1 + E2) * w2, A3 = (E2 + E3) * w3;                           \
    float A4 = (E3 + E4) * w4, A5 = (E4 + E5) * w5;                           \
    float A6 = (E5 + E6) * w6, A7 = (E6 + E7) * w7;                           \
    E0 = fmaf(bu, w0, A0);                                                    \
    E1 = fmaf(E0, w1, A1);                                                    \
    E2 = fmaf(E1, w2, A2);                                                    \
    E3 = fmaf(E2, w3, A3);                                                    \
    E4 = fmaf(E3, w4, A4);                                                    \
    E5 = fmaf(E4, w5, A5);                                                    \
    E6 = fmaf(E5, w6, A6);                                                    \
    E7 = fmaf(E6, w7, A7);                                                    \
    ap = bu; ++s;                                                             \
}

    for (;;) {
        PHASE(q0); if (s > smax) break;
        PHASE(q1); if (s > smax) break;
        PHASE(q2); if (s > smax) break;
        PHASE(q3); if (s > smax) break;
    }
#undef PHASE

    if (wl == lout) {
        float eo = E0;
        if (qout == 1) eo = E1; if (qout == 2) eo = E2; if (qout == 3) eo = E3;
        if (qout == 4) eo = E4; if (qout == 5) eo = E5; if (qout == 6) eo = E6;
        if (qout == 7) eo = E7;
        dists[b] = -GLN2 * LOG2F(eo) * (0.5f / (float)L);
    }
}

// ---------------- fallback (round-1 proven kernel) if ws is too small ----------------
#define FXSTR 36
__global__ __launch_bounds__(512, 1) void sdtw_fb(
    const float* __restrict__ data, const int* __restrict__ lens,
    float* __restrict__ dists)
{
    __shared__ __align__(16) float LX[NSEQ * FXSTR];
    __shared__ float LSQ[NSEQ];
    __shared__ float RB[3][NSEQ + 2];

    const int b = blockIdx.x;
    const int t = threadIdx.x;
    const float* xb = data + (size_t)b * (NSEQ * FDIM);

    #pragma unroll
    for (int r = 0; r < 8; ++r) {
        int q = r * 512 + t;
        int j = q >> 3, c4 = (q & 7) << 2;
        float4 v = ((const float4*)xb)[q];
        *(float4*)&LX[j * FXSTR + c4] = v;
    }
    for (int idx = t; idx < 3 * (NSEQ + 2); idx += 512) ((float*)RB)[idx] = BIGV;
    __syncthreads();

    const int i = t;
    float4 xi[8];
    float sqi = 0.f;
    {
        const float* src = &LX[i * FXSTR];
        #pragma unroll
        for (int c = 0; c < 8; ++c) {
            float4 v = *(const float4*)&src[c * 4];
            xi[c] = v;
            sqi += v.x * v.x + v.y * v.y + v.z * v.z + v.w * v.w;
        }
        LSQ[i] = sqi;
    }
    int L = lens[b];
    L = L < 1 ? 1 : (L > NSEQ ? NSEQ : L);
    __syncthreads();

    float lastR = 0.0f;
    if (i == 0) {
        float dot = 0.f;
        #pragma unroll
        for (int c = 0; c < 8; ++c) {
            float4 v = xi[c];
            dot += v.x * v.x + v.y * v.y + v.z * v.z + v.w * v.w;
        }
        float d00 = sqi + sqi - 2.f * dot;
        lastR = d00;
        RB[0][1] = d00;
    }
    __syncthreads();

    float* b0 = RB[1]; float* b1 = RB[0]; float* b2 = RB[2];
    const int kend = 2 * L - 2;
    for (int k = 1; k <= kend; ++k) {
        int j = k - i;
        if (j >= 0 && j < L && i < L) {
            const float* xj = &LX[j * FXSTR];
            float d0 = 0.f, d1 = 0.f, d2 = 0.f, d3 = 0.f;
            #pragma unroll
            for (int c = 0; c < 8; ++c) {
                float4 v = *(const float4*)&xj[c * 4];
                d0 = fmaf(v.x, xi[c].x, d0);
                d1 = fmaf(v.y, xi[c].y, d1);
                d2 = fmaf(v.z, xi[c].z, d2);
                d3 = fmaf(v.w, xi[c].w, d3);
            }
            float dot = (d0 + d1) + (d2 + d3);
            float Dij = sqi + LSQ[j] - 2.f * dot;
            float a = b2[i], bb = b1[i], cc = b1[i + 1];
            float m = fminf(fminf(a, bb), cc);
            float e = EXP2F((m - a) * INVGL) + EXP2F((m - bb) * INVGL)
                    + EXP2F((m - cc) * INVGL);
            float r = Dij + m - GLN2 * LOG2F(e);
            b0[i + 1] = r;
            lastR = r;
        }
        __syncthreads();
        float* tmp = b2; b2 = b1; b1 = b0; b0 = tmp;
    }
    if (i == L - 1) dists[b] = lastR / (2.0f * (float)L);
}

// ---------------- finalize: hard-triplet reduction -> scalar ----------------
__global__ __launch_bounds__(64) void finalize_kernel(
    const float* __restrict__ dists, float* __restrict__ out)
{
    __shared__ float acc[NWK];
    const int t = threadIdx.x;
    const int g = NGK + 1;  // 6
    if (t < NWK) {
        float dd[STEPW];
        #pragma unroll
        for (int s = 0; s < STEPW; ++s) dd[s] = dists[t * STEPW + s];

        float sum_lks = 0.f, nnz = 0.f;
        for (int ii = 0; ii < g; ++ii) {
            float mx = 0.f;
            for (int jj = 0; jj < g; ++jj) {
                float dmg_ij = 0.5f * (dd[ii] + dd[jj]);
                for (int f = 0; f < NFK; ++f) {
                    float s = dmg_ij + 1.0f - 0.5f * (dd[ii] + dd[g + f]);
                    s = fmaxf(s, 0.f);
                    mx = fmaxf(mx, s);
                }
            }
            sum_lks += mx;
            nnz += (mx != 0.f) ? 1.f : 0.f;
        }
        sum_lks *= (float)(g * NFK);
        nnz     *= (float)(g * NFK);
        float lv = sum_lks / (nnz + 1.f);

        float only_pos = 0.f;
        for (int ii = 1; ii < g; ++ii)
            for (int jj = 0; jj < ii; ++jj)
                only_pos += 0.5f * (dd[ii] + dd[jj]);
        only_pos *= (0.01f / (float)NGK);

        acc[t] = lv + only_pos;
    }
    __syncthreads();
    if (t == 0) {
        float s = 0.f;
        #pragma unroll
        for (int w = 0; w < NWK; ++w) s += acc[w];
        out[0] = s * (1.0f / (float)NWK);
    }
}

extern "C" void kernel_launch(void* const* d_in, const int* in_sizes, int n_in,
                              void* d_out, int out_size, void* d_ws, size_t ws_size,
                              hipStream_t stream)
{
    const float* data = (const float*)d_in[0];   // (128, 512, 32) f32
    const int*   lens = (const int*)d_in[1];     // (128,) i32
    float* out   = (float*)d_out;
    float* dists = (float*)d_ws;                 // 128 f32 at offset 0

    const size_t OFF_XBF = 1024;
    const size_t OFF_SQ  = OFF_XBF + (size_t)NBAT * NSEQ * FDIM * 2;   // +4 MB
    const size_t OFF_WSK = OFF_SQ  + (size_t)NBAT * NSEQ * 4;          // +256 KB
    const size_t NEED    = OFF_WSK + (size_t)NBAT * SROWS * NSEQ * 2;  // +75.5 MB

    if (ws_size >= NEED) {
        uint16_t* xbf = (uint16_t*)((char*)d_ws + OFF_XBF);
        float*    sq  = (float*)((char*)d_ws + OFF_SQ);
        uint16_t* wsk = (uint16_t*)((char*)d_ws + OFF_WSK);
        prep_kernel<<<NBAT, 256, 0, stream>>>(data, xbf, sq);
        dgen_kernel<<<dim3(32, NBAT), 256, 0, stream>>>(xbf, sq, lens, wsk);
        dp_kernel<<<NBAT, 64, 0, stream>>>(wsk, lens, dists);
    } else {
        sdtw_fb<<<NBAT, 512, 0, stream>>>(data, lens, dists);
    }
    finalize_kernel<<<1, 64, 0, stream>>>(dists, out);
}

// Round 9
// 96.738 us; speedup vs baseline: 1.7685x; 1.7685x over previous
//
#include <hip/hip_runtime.h>
#include <stdint.h>

#define NGK   5
#define NFK   10
#define NWK   8
#define STEPW 16      // NG + NF + 1
#define NSEQ  512
#define FDIM  32
#define NBAT  128
#define SROWS 576     // skewed rows: max real row = 511 + 63 = 574
#define DEPTH 12      // register prefetch ring depth (asm-pinned)
#define BIGV  1000000000.0f

#define INVGL 0.28853900817779268f   // 1/(gamma*ln2)
#define GLN2  3.4657359027997265f    // gamma*ln2

#define EXP2F(x) __builtin_amdgcn_exp2f(x)
#define LOG2F(x) __builtin_amdgcn_logf(x)   // v_log_f32 = log2 (validated r1-r8)

typedef short bf16x8 __attribute__((ext_vector_type(8)));
typedef float f32x4  __attribute__((ext_vector_type(4)));
union U32F { uint32_t u; float f; };

__device__ __forceinline__ uint32_t f2bf(float f) {  // f32 -> bf16 RNE
    U32F c; c.f = f;
    return (c.u + 0x7FFFu + ((c.u >> 16) & 1u)) >> 16;
}
__device__ __forceinline__ float bflo(uint32_t u) { U32F c; c.u = u << 16; return c.f; }
__device__ __forceinline__ float bfhi(uint32_t u) { U32F c; c.u = u & 0xFFFF0000u; return c.f; }

// lane n <- lane n-1 (DPP wave_shr:1 = 0x138); lane 0 -> 0 (= E-domain boundary).
__device__ __forceinline__ float dpp_shr1_f(float v) {
    U32F c; c.f = v;
    c.u = (uint32_t)__builtin_amdgcn_update_dpp(0, (int)c.u, 0x138, 0xF, 0xF, true);
    return c.f;
}

// ---------- kernel 0: stage x -> bf16 rows (64 B) + row norms ----------
__global__ __launch_bounds__(256, 1) void prep_kernel(
    const float* __restrict__ data, uint16_t* __restrict__ xbf,
    float* __restrict__ sq)
{
    __shared__ uint32_t LB[NSEQ * 16];   // 32 KB bf16-pair rows
    const int b = blockIdx.x;
    const int t = threadIdx.x;
    const float4* xb4 = (const float4*)(data + (size_t)b * (NSEQ * FDIM));
    uint2* xg = (uint2*)(xbf + (size_t)b * (NSEQ * FDIM));

    #pragma unroll
    for (int it = 0; it < 16; ++it) {
        int q = it * 256 + t;            // float4 index, 4096 total
        float4 v = xb4[q];
        uint32_t u0 = f2bf(v.x) | (f2bf(v.y) << 16);
        uint32_t u1 = f2bf(v.z) | (f2bf(v.w) << 16);
        LB[q * 2] = u0; LB[q * 2 + 1] = u1;
        uint2 st; st.x = u0; st.y = u1;
        xg[q] = st;
    }
    __syncthreads();
    #pragma unroll
    for (int rr = 0; rr < 2; ++rr) {
        int r = t + rr * 256;
        float acc = 0.f;
        #pragma unroll
        for (int c = 0; c < 16; ++c) {
            uint32_t u = LB[r * 16 + c];
            float lo = bflo(u), hi = bfhi(u);
            acc = fmaf(lo, lo, acc);
            acc = fmaf(hi, hi, acc);
        }
        sq[(size_t)b * NSEQ + r] = acc;
    }
}

// ---------- kernel 1: MFMA -> skewed bf16 W matrix (L2-hot frag reads) ----------
// Wsk[b][s][i] = 2^(-D[i][ s-(i>>3) ] * INVGL), 0 where i>=L or j>=L.
__global__ __launch_bounds__(256, 1) void dgen_kernel(
    const uint16_t* __restrict__ xbf, const float* __restrict__ sq,
    const int* __restrict__ lens, uint16_t* __restrict__ wsk)
{
    const int tj = blockIdx.x, b = blockIdx.y;
    int L = lens[b]; L = L < 1 ? 1 : (L > NSEQ ? NSEQ : L);
    const int smax = (L - 1) + ((L - 1) >> 3);
    int maxrow = smax + 8; if (maxrow > SROWS - 1) maxrow = SROWS - 1;
    if (tj * 16 > maxrow) return;

    const int t = threadIdx.x;
    const int w = t >> 6, lane = t & 63, rl = lane & 15, kq = lane >> 4, rr0 = kq * 4;
    const int j = tj * 16 + rl;

    const short* xb  = (const short*)(xbf + (size_t)b * (NSEQ * FDIM));
    const float* sqb = sq + (size_t)b * NSEQ;
    uint16_t* wb = wsk + (size_t)b * (SROWS * NSEQ);

    bf16x8 bfrag = *(const bf16x8*)(xb + j * FDIM + kq * 8);   // validated B-frag
    float sqJ = sqb[j];
    const bool jok = j < L;

    for (int it = 0; it < 8; ++it) {
        int ti = w * 8 + it;
        if (tj * 16 + ti * 2 > maxrow) break;      // wave-uniform
        bf16x8 afrag = *(const bf16x8*)(xb + (ti * 16 + rl) * FDIM + kq * 8);
        f32x4 c = {0.f, 0.f, 0.f, 0.f};
        c = __builtin_amdgcn_mfma_f32_16x16x32_bf16(afrag, bfrag, c, 0, 0, 0);
        f32x4 s4 = *(const f32x4*)(sqb + ti * 16 + rr0);
        float wv[4];
        #pragma unroll
        for (int q2 = 0; q2 < 4; ++q2) {
            int i = ti * 16 + rr0 + q2;
            float dv = s4[q2] + sqJ - 2.f * c[q2];
            float e = EXP2F(-INVGL * dv);
            wv[q2] = (jok && (i < L)) ? e : 0.f;
        }
        int sr = j + ti * 2 + (rr0 >> 3);          // skewed row
        uint2 st;
        st.x = f2bf(wv[0]) | (f2bf(wv[1]) << 16);
        st.y = f2bf(wv[2]) | (f2bf(wv[3]) << 16);
        *(uint2*)(wb + (size_t)sr * NSEQ + ti * 16 + rr0) = st;
    }
}

// ---------- kernel 2: exp-domain soft-DTW, one wave/batch, asm-pinned 12-deep ring ----------
// E = 2^(-R*INVGL); E' = (E_diag + E_up + E_left) * W; lane wl owns rows 8wl..8wl+7.
// Loads are inline-asm global_load_dwordx4 into 12 named uint4 regs with counted
// vmcnt(11) waits -> 12 rows (~1300 cyc) guaranteed in flight; compiler cannot sink.
// Last-finishing block runs the triplet-loss finalize (device-scope atomics).
__global__ __launch_bounds__(64, 1) void dp_kernel(
    const uint16_t* __restrict__ wsk, const int* __restrict__ lens,
    float* __restrict__ dists, uint32_t* __restrict__ ctr,
    float* __restrict__ out)
{
    const int b = blockIdx.x, wl = threadIdx.x;
    const uint16_t* wb = wsk + (size_t)b * (SROWS * NSEQ) + wl * 8;
    int L = lens[b]; L = L < 1 ? 1 : (L > NSEQ ? NSEQ : L);
    const int lout = (L - 1) >> 3, qout = (L - 1) & 7, smax = (L - 1) + lout;

#define ISSUE(Q, row) {                                                       \
    int gl_ = (row); if (gl_ > SROWS - 1) gl_ = SROWS - 1;                    \
    const uint16_t* pg_ = wb + (size_t)gl_ * NSEQ;                            \
    asm volatile("global_load_dwordx4 %0, %1, off" : "=&v"(Q) : "v"(pg_));    \
}

    uint4 Q0, Q1, Q2, Q3, Q4, Q5, Q6, Q7, Q8, Q9, Qa, Qb;
    ISSUE(Q0, 0)  ISSUE(Q1, 1)  ISSUE(Q2, 2)  ISSUE(Q3, 3)
    ISSUE(Q4, 4)  ISSUE(Q5, 5)  ISSUE(Q6, 6)  ISSUE(Q7, 7)
    ISSUE(Q8, 8)  ISSUE(Q9, 9)  ISSUE(Qa, 10) ISSUE(Qb, 11)

    float E0 = 0.f, E1 = 0.f, E2 = 0.f, E3 = 0.f,
          E4 = 0.f, E5 = 0.f, E6 = 0.f, E7 = 0.f;
    float ap = (wl == 0) ? 1.0f : 0.f;   // virtual start: diag pred of (0,0) = exp(0)

    int s = 0;

#define PHASE(Q) {                                                            \
    asm volatile("s_waitcnt vmcnt(11)" ::: "memory");  /* row s landed */     \
    __builtin_amdgcn_sched_barrier(0);                                        \
    float w0 = bflo(Q.x), w1 = bfhi(Q.x), w2 = bflo(Q.y), w3 = bfhi(Q.y);     \
    float w4 = bflo(Q.z), w5 = bfhi(Q.z), w6 = bflo(Q.w), w7 = bfhi(Q.w);     \
    ISSUE(Q, s + DEPTH);                                                      \
    float bu = dpp_shr1_f(E7);                                                \
    float A0 = (ap + E0) * w0, A1 = (E0 + E1) * w1;                           \
    float A2 = (E1 + E2) * w2, A3 = (E2 + E3) * w3;                           \
    float A4 = (E3 + E4) * w4, A5 = (E4 + E5) * w5;                           \
    float A6 = (E5 + E6) * w6, A7 = (E6 + E7) * w7;                           \
    E0 = fmaf(bu, w0, A0);                                                    \
    E1 = fmaf(E0, w1, A1);                                                    \
    E2 = fmaf(E1, w2, A2);                                                    \
    E3 = fmaf(E2, w3, A3);                                                    \
    E4 = fmaf(E3, w4, A4);                                                    \
    E5 = fmaf(E4, w5, A5);                                                    \
    E6 = fmaf(E5, w6, A6);                                                    \
    E7 = fmaf(E6, w7, A7);                                                    \
    ap = bu; ++s;                                                             \
}

    for (;;) {
        PHASE(Q0); if (s > smax) break;
        PHASE(Q1); if (s > smax) break;
        PHASE(Q2); if (s > smax) break;
        PHASE(Q3); if (s > smax) break;
        PHASE(Q4); if (s > smax) break;
        PHASE(Q5); if (s > smax) break;
        PHASE(Q6); if (s > smax) break;
        PHASE(Q7); if (s > smax) break;
        PHASE(Q8); if (s > smax) break;
        PHASE(Q9); if (s > smax) break;
        PHASE(Qa); if (s > smax) break;
        PHASE(Qb); if (s > smax) break;
    }
#undef PHASE
#undef ISSUE
    asm volatile("s_waitcnt vmcnt(0)" ::: "memory");   // drain before reg reuse/exit

    if (wl == lout) {
        float eo = E0;
        if (qout == 1) eo = E1; if (qout == 2) eo = E2; if (qout == 3) eo = E3;
        if (qout == 4) eo = E4; if (qout == 5) eo = E5; if (qout == 6) eo = E6;
        if (qout == 7) eo = E7;
        float dv = -GLN2 * LOG2F(eo) * (0.5f / (float)L);
        __hip_atomic_store(&dists[b], dv, __ATOMIC_RELEASE, __HIP_MEMORY_SCOPE_AGENT);
    }

    // ---- fused finalize: last-arriving block reduces the 128 dists ----
    int old = 0;
    if (wl == 0) {
        old = (int)__hip_atomic_fetch_add(ctr, 1u, __ATOMIC_ACQ_REL,
                                          __HIP_MEMORY_SCOPE_AGENT);
    }
    old = __shfl(old, 0);
    if (old == NBAT - 1) {
        const int g = NGK + 1;  // 6
        float part = 0.f;
        if (wl < NWK) {
            float dd[STEPW];
            #pragma unroll
            for (int s2 = 0; s2 < STEPW; ++s2)
                dd[s2] = __hip_atomic_load(&dists[wl * STEPW + s2],
                                           __ATOMIC_RELAXED, __HIP_MEMORY_SCOPE_AGENT);
            float sum_lks = 0.f, nnz = 0.f;
            for (int ii = 0; ii < g; ++ii) {
                float mx = 0.f;
                for (int jj = 0; jj < g; ++jj) {
                    float dmg_ij = 0.5f * (dd[ii] + dd[jj]);
                    for (int f = 0; f < NFK; ++f) {
                        float sc = dmg_ij + 1.0f - 0.5f * (dd[ii] + dd[g + f]);
                        sc = fmaxf(sc, 0.f);
                        mx = fmaxf(mx, sc);
                    }
                }
                sum_lks += mx;
                nnz += (mx != 0.f) ? 1.f : 0.f;
            }
            sum_lks *= (float)(g * NFK);
            nnz     *= (float)(g * NFK);
            float lv = sum_lks / (nnz + 1.f);
            float only_pos = 0.f;
            for (int ii = 1; ii < g; ++ii)
                for (int jj = 0; jj < ii; ++jj)
                    only_pos += 0.5f * (dd[ii] + dd[jj]);
            only_pos *= (0.01f / (float)NGK);
            part = lv + only_pos;
        }
        float tot = 0.f;
        #pragma unroll
        for (int w2 = 0; w2 < NWK; ++w2) tot += __shfl(part, w2);
        if (wl == 0) out[0] = tot * (1.0f / (float)NWK);
    }
}

// ---------------- fallback (round-1 proven kernel) if ws is too small ----------------
#define FXSTR 36
__global__ __launch_bounds__(512, 1) void sdtw_fb(
    const float* __restrict__ data, const int* __restrict__ lens,
    float* __restrict__ dists)
{
    __shared__ __align__(16) float LX[NSEQ * FXSTR];
    __shared__ float LSQ[NSEQ];
    __shared__ float RB[3][NSEQ + 2];

    const int b = blockIdx.x;
    const int t = threadIdx.x;
    const float* xb = data + (size_t)b * (NSEQ * FDIM);

    #pragma unroll
    for (int r = 0; r < 8; ++r) {
        int q = r * 512 + t;
        int j = q >> 3, c4 = (q & 7) << 2;
        float4 v = ((const float4*)xb)[q];
        *(float4*)&LX[j * FXSTR + c4] = v;
    }
    for (int idx = t; idx < 3 * (NSEQ + 2); idx += 512) ((float*)RB)[idx] = BIGV;
    __syncthreads();

    const int i = t;
    float4 xi[8];
    float sqi = 0.f;
    {
        const float* src = &LX[i * FXSTR];
        #pragma unroll
        for (int c = 0; c < 8; ++c) {
            float4 v = *(const float4*)&src[c * 4];
            xi[c] = v;
            sqi += v.x * v.x + v.y * v.y + v.z * v.z + v.w * v.w;
        }
        LSQ[i] = sqi;
    }
    int L = lens[b];
    L = L < 1 ? 1 : (L > NSEQ ? NSEQ : L);
    __syncthreads();

    float lastR = 0.0f;
    if (i == 0) {
        float dot = 0.f;
        #pragma unroll
        for (int c = 0; c < 8; ++c) {
            float4 v = xi[c];
            dot += v.x * v.x + v.y * v.y + v.z * v.z + v.w * v.w;
        }
        float d00 = sqi + sqi - 2.f * dot;
        lastR = d00;
        RB[0][1] = d00;
    }
    __syncthreads();

    float* b0 = RB[1]; float* b1 = RB[0]; float* b2 = RB[2];
    const int kend = 2 * L - 2;
    for (int k = 1; k <= kend; ++k) {
        int j = k - i;
        if (j >= 0 && j < L && i < L) {
            const float* xj = &LX[j * FXSTR];
            float d0 = 0.f, d1 = 0.f, d2 = 0.f, d3 = 0.f;
            #pragma unroll
            for (int c = 0; c < 8; ++c) {
                float4 v = *(const float4*)&xj[c * 4];
                d0 = fmaf(v.x, xi[c].x, d0);
                d1 = fmaf(v.y, xi[c].y, d1);
                d2 = fmaf(v.z, xi[c].z, d2);
                d3 = fmaf(v.w, xi[c].w, d3);
            }
            float dot = (d0 + d1) + (d2 + d3);
            float Dij = sqi + LSQ[j] - 2.f * dot;
            float a = b2[i], bb = b1[i], cc = b1[i + 1];
            float m = fminf(fminf(a, bb), cc);
            float e = EXP2F((m - a) * INVGL) + EXP2F((m - bb) * INVGL)
                    + EXP2F((m - cc) * INVGL);
            float r = Dij + m - GLN2 * LOG2F(e);
            b0[i + 1] = r;
            lastR = r;
        }
        __syncthreads();
        float* tmp = b2; b2 = b1; b1 = b0; b0 = tmp;
    }
    if (i == L - 1) dists[b] = lastR / (2.0f * (float)L);
}

// ---------------- standalone finalize (fallback path only) ----------------
__global__ __launch_bounds__(64) void finalize_kernel(
    const float* __restrict__ dists, float* __restrict__ out)
{
    __shared__ float acc[NWK];
    const int t = threadIdx.x;
    const int g = NGK + 1;  // 6
    if (t < NWK) {
        float dd[STEPW];
        #pragma unroll
        for (int s = 0; s < STEPW; ++s) dd[s] = dists[t * STEPW + s];

        float sum_lks = 0.f, nnz = 0.f;
        for (int ii = 0; ii < g; ++ii) {
            float mx = 0.f;
            for (int jj = 0; jj < g; ++jj) {
                float dmg_ij = 0.5f * (dd[ii] + dd[jj]);
                for (int f = 0; f < NFK; ++f) {
                    float s = dmg_ij + 1.0f - 0.5f * (dd[ii] + dd[g + f]);
                    s = fmaxf(s, 0.f);
                    mx = fmaxf(mx, s);
                }
            }
            sum_lks += mx;
            nnz += (mx != 0.f) ? 1.f : 0.f;
        }
        sum_lks *= (float)(g * NFK);
        nnz     *= (float)(g * NFK);
        float lv = sum_lks / (nnz + 1.f);

        float only_pos = 0.f;
        for (int ii = 1; ii < g; ++ii)
            for (int jj = 0; jj < ii; ++jj)
                only_pos += 0.5f * (dd[ii] + dd[jj]);
        only_pos *= (0.01f / (float)NGK);

        acc[t] = lv + only_pos;
    }
    __syncthreads();
    if (t == 0) {
        float s = 0.f;
        #pragma unroll
        for (int w = 0; w < NWK; ++w) s += acc[w];
        out[0] = s * (1.0f / (float)NWK);
    }
}

extern "C" void kernel_launch(void* const* d_in, const int* in_sizes, int n_in,
                              void* d_out, int out_size, void* d_ws, size_t ws_size,
                              hipStream_t stream)
{
    const float* data = (const float*)d_in[0];   // (128, 512, 32) f32
    const int*   lens = (const int*)d_in[1];     // (128,) i32
    float* out   = (float*)d_out;
    float* dists = (float*)d_ws;                 // 128 f32 at offset 0
    uint32_t* ctr = (uint32_t*)((char*)d_ws + 512);

    const size_t OFF_XBF = 1024;
    const size_t OFF_SQ  = OFF_XBF + (size_t)NBAT * NSEQ * FDIM * 2;   // +4 MB
    const size_t OFF_WSK = OFF_SQ  + (size_t)NBAT * NSEQ * 4;          // +256 KB
    const size_t NEED    = OFF_WSK + (size_t)NBAT * SROWS * NSEQ * 2;  // +75.5 MB

    if (ws_size >= NEED) {
        uint16_t* xbf = (uint16_t*)((char*)d_ws + OFF_XBF);
        float*    sq  = (float*)((char*)d_ws + OFF_SQ);
        uint16_t* wsk = (uint16_t*)((char*)d_ws + OFF_WSK);
        hipMemsetAsync(ctr, 0, 4, stream);
        prep_kernel<<<NBAT, 256, 0, stream>>>(data, xbf, sq);
        dgen_kernel<<<dim3(32, NBAT), 256, 0, stream>>>(xbf, sq, lens, wsk);
        dp_kernel<<<NBAT, 64, 0, stream>>>(wsk, lens, dists, ctr, out);
    } else {
        sdtw_fb<<<NBAT, 512, 0, stream>>>(data, lens, dists);
        finalize_kernel<<<1, 64, 0, stream>>>(dists, out);
    }
}

// Round 10
// 82.870 us; speedup vs baseline: 2.0645x; 1.1674x over previous
//
#include <hip/hip_runtime.h>
#include <stdint.h>

#define NGK   5
#define NFK   10
#define NWK   8
#define STEPW 16      // NG + NF + 1
#define NSEQ  512
#define FDIM  32
#define NBAT  128
#define SROWS 576     // old-layout skewed rows (r9 middle path)
#define DEPTH 12      // r9 dp ring depth
#define NR2   319     // new-layout dstep rows: max S_out = (511+126)/2 = 318
#define BIGV  1000000000.0f

#define INVGL 0.28853900817779268f   // 1/(gamma*ln2)
#define GLN2  3.4657359027997265f    // gamma*ln2

#define EXP2F(x) __builtin_amdgcn_exp2f(x)
#define LOG2F(x) __builtin_amdgcn_logf(x)   // v_log_f32 = log2 (validated r1-r9)

typedef short bf16x8 __attribute__((ext_vector_type(8)));
typedef float f32x4  __attribute__((ext_vector_type(4)));
union U32F { uint32_t u; float f; };

__device__ __forceinline__ uint32_t f2bf(float f) {  // f32 -> bf16 RNE
    U32F c; c.f = f;
    return (c.u + 0x7FFFu + ((c.u >> 16) & 1u)) >> 16;
}
__device__ __forceinline__ float bflo(uint32_t u) { U32F c; c.u = u << 16; return c.f; }
__device__ __forceinline__ float bfhi(uint32_t u) { U32F c; c.u = u & 0xFFFF0000u; return c.f; }

// lane n <- lane n-1 (DPP wave_shr:1 = 0x138); lane 0 -> 0 (= E-domain boundary).
__device__ __forceinline__ float dpp_shr1_f(float v) {
    U32F c; c.f = v;
    c.u = (uint32_t)__builtin_amdgcn_update_dpp(0, (int)c.u, 0x138, 0xF, 0xF, true);
    return c.f;
}

// ---------- kernel 0: stage x -> bf16 rows (64 B) + row norms ----------
__global__ __launch_bounds__(256, 1) void prep_kernel(
    const float* __restrict__ data, uint16_t* __restrict__ xbf,
    float* __restrict__ sq)
{
    __shared__ uint32_t LB[NSEQ * 16];   // 32 KB bf16-pair rows
    const int b = blockIdx.x;
    const int t = threadIdx.x;
    const float4* xb4 = (const float4*)(data + (size_t)b * (NSEQ * FDIM));
    uint2* xg = (uint2*)(xbf + (size_t)b * (NSEQ * FDIM));

    #pragma unroll
    for (int it = 0; it < 16; ++it) {
        int q = it * 256 + t;            // float4 index, 4096 total
        float4 v = xb4[q];
        uint32_t u0 = f2bf(v.x) | (f2bf(v.y) << 16);
        uint32_t u1 = f2bf(v.z) | (f2bf(v.w) << 16);
        LB[q * 2] = u0; LB[q * 2 + 1] = u1;
        uint2 st; st.x = u0; st.y = u1;
        xg[q] = st;
    }
    __syncthreads();
    #pragma unroll
    for (int rr = 0; rr < 2; ++rr) {
        int r = t + rr * 256;
        float acc = 0.f;
        #pragma unroll
        for (int c = 0; c < 16; ++c) {
            uint32_t u = LB[r * 16 + c];
            float lo = bflo(u), hi = bfhi(u);
            acc = fmaf(lo, lo, acc);
            acc = fmaf(hi, hi, acc);
        }
        sq[(size_t)b * NSEQ + r] = acc;
    }
}

// ================= NEW PATH: double-step layout =================
// W2[b][S][l][sub][8] bf16: cell (i,j) -> l=i>>3, q=i&7, c=j+2l, S=c>>1, sub=c&1.
// u16 index = S*1024 + l*16 + sub*8 + q.
__global__ __launch_bounds__(256, 1) void dgen2_kernel(
    const uint16_t* __restrict__ xbf, const float* __restrict__ sq,
    const int* __restrict__ lens, uint16_t* __restrict__ wsk)
{
    const int tj = blockIdx.x, b = blockIdx.y;
    int L = lens[b]; L = L < 1 ? 1 : (L > NSEQ ? NSEQ : L);
    const int lout = (L - 1) >> 3;
    const int maxS = ((L - 1) + 2 * lout) >> 1;          // = S_out
    if (tj * 16 > 2 * maxS + 1) return;

    const int t = threadIdx.x;
    const int w = t >> 6, lane = t & 63, rl = lane & 15, kq = lane >> 4, rr0 = kq * 4;
    const int j = tj * 16 + rl;

    const short* xb  = (const short*)(xbf + (size_t)b * (NSEQ * FDIM));
    const float* sqb = sq + (size_t)b * NSEQ;
    uint16_t* wb = wsk + (size_t)b * (NR2 * 1024);

    bf16x8 bfrag = *(const bf16x8*)(xb + j * FDIM + kq * 8);   // validated B-frag
    float sqJ = sqb[j];
    const bool jok = j < L;
    const int q0 = rr0 & 7;                // 0 or 4
    const int ladd = rr0 >> 3;             // 0 or 1

    for (int it = 0; it < 8; ++it) {
        int ti = w * 8 + it;
        if (tj * 16 + 4 * ti > 2 * maxS + 1) break;      // wave-uniform skip
        bf16x8 afrag = *(const bf16x8*)(xb + (ti * 16 + rl) * FDIM + kq * 8);
        f32x4 c = {0.f, 0.f, 0.f, 0.f};
        c = __builtin_amdgcn_mfma_f32_16x16x32_bf16(afrag, bfrag, c, 0, 0, 0);
        f32x4 s4 = *(const f32x4*)(sqb + ti * 16 + rr0);
        float wv[4];
        #pragma unroll
        for (int q2 = 0; q2 < 4; ++q2) {
            int i = ti * 16 + rr0 + q2;
            float dv = s4[q2] + sqJ - 2.f * c[q2];
            float e = EXP2F(-INVGL * dv);
            wv[q2] = (jok && (i < L)) ? e : 0.f;
        }
        int l  = ti * 2 + ladd;
        int cc = j + 2 * l;
        int S  = cc >> 1, sub = cc & 1;
        if (S <= maxS) {
            uint2 st;
            st.x = f2bf(wv[0]) | (f2bf(wv[1]) << 16);
            st.y = f2bf(wv[2]) | (f2bf(wv[3]) << 16);
            *(uint2*)(wb + (size_t)S * 1024 + l * 16 + sub * 8 + q0) = st;
        }
    }
}

// dp2: one wave/batch, 2 columns per double-step, two interleaved FMA chains,
// asm-pinned 8-pair register ring (16 loads in flight, vmcnt(14)).
__global__ __launch_bounds__(64, 1) void dp2_kernel(
    const uint16_t* __restrict__ wsk, const int* __restrict__ lens,
    float* __restrict__ dists, uint32_t* __restrict__ ctr,
    float* __restrict__ out)
{
    const int b = blockIdx.x, wl = threadIdx.x;
    const uint16_t* wb = wsk + (size_t)b * (NR2 * 1024) + wl * 16;
    int L = lens[b]; L = L < 1 ? 1 : (L > NSEQ ? NSEQ : L);
    const int lout = (L - 1) >> 3, qout = (L - 1) & 7;
    const int cout = (L - 1) + 2 * lout;
    const int S_out = cout >> 1;

#define ISSUE2(QA, QB, row) {                                                 \
    int gl_ = (row); if (gl_ > NR2 - 1) gl_ = NR2 - 1;                        \
    const uint16_t* pg_ = wb + (size_t)gl_ * 1024;                            \
    asm volatile("global_load_dwordx4 %0, %2, off\n\t"                        \
                 "global_load_dwordx4 %1, %2, off offset:16"                  \
                 : "=&v"(QA), "=&v"(QB) : "v"(pg_));                          \
}

    uint4 A0r, B0r, A1r, B1r, A2r, B2r, A3r, B3r,
          A4r, B4r, A5r, B5r, A6r, B6r, A7r, B7r;
    ISSUE2(A0r, B0r, 0) ISSUE2(A1r, B1r, 1) ISSUE2(A2r, B2r, 2) ISSUE2(A3r, B3r, 3)
    ISSUE2(A4r, B4r, 4) ISSUE2(A5r, B5r, 5) ISSUE2(A6r, B6r, 6) ISSUE2(A7r, B7r, 7)

    float E0 = 0.f, E1 = 0.f, E2 = 0.f, E3 = 0.f,
          E4 = 0.f, E5 = 0.f, E6 = 0.f, E7 = 0.f;     // colB state (prev dstep)
    float f0 = 0.f, f1 = 0.f, f2 = 0.f, f3 = 0.f,
          f4 = 0.f, f5 = 0.f, f6 = 0.f, f7 = 0.f;     // colA state
    float ap  = (wl == 0) ? 1.0f : 0.f;  // diag pred of (8wl, j0) = buB of prev dstep
    float f7p = 0.f;                     // own F7 of prev dstep (feeds buA)

    int s = 0;

#define DSTEP(QA, QB) {                                                       \
    asm volatile("s_waitcnt vmcnt(14)" ::: "memory");                         \
    __builtin_amdgcn_sched_barrier(0);                                        \
    float wa0 = bflo(QA.x), wa1 = bfhi(QA.x), wa2 = bflo(QA.y), wa3 = bfhi(QA.y); \
    float wa4 = bflo(QA.z), wa5 = bfhi(QA.z), wa6 = bflo(QA.w), wa7 = bfhi(QA.w); \
    float wb0 = bflo(QB.x), wb1 = bfhi(QB.x), wb2 = bflo(QB.y), wb3 = bfhi(QB.y); \
    float wb4 = bflo(QB.z), wb5 = bfhi(QB.z), wb6 = bflo(QB.w), wb7 = bfhi(QB.w); \
    ISSUE2(QA, QB, s + 8);                                                    \
    float buA = dpp_shr1_f(f7p);                                              \
    float buB = dpp_shr1_f(E7);                                               \
    float a0 = (ap + E0) * wa0, a1 = (E0 + E1) * wa1;                         \
    float a2 = (E1 + E2) * wa2, a3 = (E2 + E3) * wa3;                         \
    float a4 = (E3 + E4) * wa4, a5 = (E4 + E5) * wa5;                         \
    float a6 = (E5 + E6) * wa6, a7 = (E6 + E7) * wa7;                         \
    f0 = fmaf(buA, wa0, a0);                                                  \
    f1 = fmaf(f0, wa1, a1);                                                   \
    f2 = fmaf(f1, wa2, a2);                                                   \
    f3 = fmaf(f2, wa3, a3);                                                   \
    f4 = fmaf(f3, wa4, a4);                                                   \
    f5 = fmaf(f4, wa5, a5);                                                   \
    f6 = fmaf(f5, wa6, a6);                                                   \
    f7 = fmaf(f6, wa7, a7);                                                   \
    float b0 = (buA + f0) * wb0, b1 = (f0 + f1) * wb1;                        \
    float b2 = (f1 + f2) * wb2, b3 = (f2 + f3) * wb3;                         \
    float b4 = (f3 + f4) * wb4, b5 = (f4 + f5) * wb5;                         \
    float b6 = (f5 + f6) * wb6, b7 = (f6 + f7) * wb7;                         \
    E0 = fmaf(buB, wb0, b0);                                                  \
    E1 = fmaf(E0, wb1, b1);                                                   \
    E2 = fmaf(E1, wb2, b2);                                                   \
    E3 = fmaf(E2, wb3, b3);                                                   \
    E4 = fmaf(E3, wb4, b4);                                                   \
    E5 = fmaf(E4, wb5, b5);                                                   \
    E6 = fmaf(E5, wb6, b6);                                                   \
    E7 = fmaf(E6, wb7, b7);                                                   \
    ap = buB; f7p = f7; ++s;                                                  \
}

    for (;;) {
        DSTEP(A0r, B0r); if (s > S_out) break;
        DSTEP(A1r, B1r); if (s > S_out) break;
        DSTEP(A2r, B2r); if (s > S_out) break;
        DSTEP(A3r, B3r); if (s > S_out) break;
        DSTEP(A4r, B4r); if (s > S_out) break;
        DSTEP(A5r, B5r); if (s > S_out) break;
        DSTEP(A6r, B6r); if (s > S_out) break;
        DSTEP(A7r, B7r); if (s > S_out) break;
    }
#undef DSTEP
#undef ISSUE2
    asm volatile("s_waitcnt vmcnt(0)" ::: "memory");   // drain before exit

    if (wl == lout) {
        float eo;
        if ((cout & 1) == 0) {           // output col = last colA -> f regs
            eo = f0;
            if (qout == 1) eo = f1; if (qout == 2) eo = f2; if (qout == 3) eo = f3;
            if (qout == 4) eo = f4; if (qout == 5) eo = f5; if (qout == 6) eo = f6;
            if (qout == 7) eo = f7;
        } else {                         // output col = last colB -> E regs
            eo = E0;
            if (qout == 1) eo = E1; if (qout == 2) eo = E2; if (qout == 3) eo = E3;
            if (qout == 4) eo = E4; if (qout == 5) eo = E5; if (qout == 6) eo = E6;
            if (qout == 7) eo = E7;
        }
        float dv = -GLN2 * LOG2F(eo) * (0.5f / (float)L);
        __hip_atomic_store(&dists[b], dv, __ATOMIC_RELEASE, __HIP_MEMORY_SCOPE_AGENT);
    }

    // ---- fused finalize: last-arriving block reduces the 128 dists ----
    int old = 0;
    if (wl == 0) {
        old = (int)__hip_atomic_fetch_add(ctr, 1u, __ATOMIC_ACQ_REL,
                                          __HIP_MEMORY_SCOPE_AGENT);
    }
    old = __shfl(old, 0);
    if (old == NBAT - 1) {
        const int g = NGK + 1;  // 6
        float part = 0.f;
        if (wl < NWK) {
            float dd[STEPW];
            #pragma unroll
            for (int s2 = 0; s2 < STEPW; ++s2)
                dd[s2] = __hip_atomic_load(&dists[wl * STEPW + s2],
                                           __ATOMIC_RELAXED, __HIP_MEMORY_SCOPE_AGENT);
            float sum_lks = 0.f, nnz = 0.f;
            for (int ii = 0; ii < g; ++ii) {
                float mx = 0.f;
                for (int jj = 0; jj < g; ++jj) {
                    float dmg_ij = 0.5f * (dd[ii] + dd[jj]);
                    for (int f = 0; f < NFK; ++f) {
                        float sc = dmg_ij + 1.0f - 0.5f * (dd[ii] + dd[g + f]);
                        sc = fmaxf(sc, 0.f);
                        mx = fmaxf(mx, sc);
                    }
                }
                sum_lks += mx;
                nnz += (mx != 0.f) ? 1.f : 0.f;
            }
            sum_lks *= (float)(g * NFK);
            nnz     *= (float)(g * NFK);
            float lv = sum_lks / (nnz + 1.f);
            float only_pos = 0.f;
            for (int ii = 1; ii < g; ++ii)
                for (int jj = 0; jj < ii; ++jj)
                    only_pos += 0.5f * (dd[ii] + dd[jj]);
            only_pos *= (0.01f / (float)NGK);
            part = lv + only_pos;
        }
        float tot = 0.f;
        #pragma unroll
        for (int w2 = 0; w2 < NWK; ++w2) tot += __shfl(part, w2);
        if (wl == 0) out[0] = tot * (1.0f / (float)NWK);
    }
}

// ================= MIDDLE PATH: r9 validated single-step =================
__global__ __launch_bounds__(256, 1) void dgen_kernel(
    const uint16_t* __restrict__ xbf, const float* __restrict__ sq,
    const int* __restrict__ lens, uint16_t* __restrict__ wsk)
{
    const int tj = blockIdx.x, b = blockIdx.y;
    int L = lens[b]; L = L < 1 ? 1 : (L > NSEQ ? NSEQ : L);
    const int smax = (L - 1) + ((L - 1) >> 3);
    int maxrow = smax + 8; if (maxrow > SROWS - 1) maxrow = SROWS - 1;
    if (tj * 16 > maxrow) return;

    const int t = threadIdx.x;
    const int w = t >> 6, lane = t & 63, rl = lane & 15, kq = lane >> 4, rr0 = kq * 4;
    const int j = tj * 16 + rl;

    const short* xb  = (const short*)(xbf + (size_t)b * (NSEQ * FDIM));
    const float* sqb = sq + (size_t)b * NSEQ;
    uint16_t* wb = wsk + (size_t)b * (SROWS * NSEQ);

    bf16x8 bfrag = *(const bf16x8*)(xb + j * FDIM + kq * 8);
    float sqJ = sqb[j];
    const bool jok = j < L;

    for (int it = 0; it < 8; ++it) {
        int ti = w * 8 + it;
        if (tj * 16 + ti * 2 > maxrow) break;
        bf16x8 afrag = *(const bf16x8*)(xb + (ti * 16 + rl) * FDIM + kq * 8);
        f32x4 c = {0.f, 0.f, 0.f, 0.f};
        c = __builtin_amdgcn_mfma_f32_16x16x32_bf16(afrag, bfrag, c, 0, 0, 0);
        f32x4 s4 = *(const f32x4*)(sqb + ti * 16 + rr0);
        float wv[4];
        #pragma unroll
        for (int q2 = 0; q2 < 4; ++q2) {
            int i = ti * 16 + rr0 + q2;
            float dv = s4[q2] + sqJ - 2.f * c[q2];
            float e = EXP2F(-INVGL * dv);
            wv[q2] = (jok && (i < L)) ? e : 0.f;
        }
        int sr = j + ti * 2 + (rr0 >> 3);
        uint2 st;
        st.x = f2bf(wv[0]) | (f2bf(wv[1]) << 16);
        st.y = f2bf(wv[2]) | (f2bf(wv[3]) << 16);
        *(uint2*)(wb + (size_t)sr * NSEQ + ti * 16 + rr0) = st;
    }
}

__global__ __launch_bounds__(64, 1) void dp_kernel(
    const uint16_t* __restrict__ wsk, const int* __restrict__ lens,
    float* __restrict__ dists, uint32_t* __restrict__ ctr,
    float* __restrict__ out)
{
    const int b = blockIdx.x, wl = threadIdx.x;
    const uint16_t* wb = wsk + (size_t)b * (SROWS * NSEQ) + wl * 8;
    int L = lens[b]; L = L < 1 ? 1 : (L > NSEQ ? NSEQ : L);
    const int lout = (L - 1) >> 3, qout = (L - 1) & 7, smax = (L - 1) + lout;

#define ISSUE(Q, row) {                                                       \
    int gl_ = (row); if (gl_ > SROWS - 1) gl_ = SROWS - 1;                    \
    const uint16_t* pg_ = wb + (size_t)gl_ * NSEQ;                            \
    asm volatile("global_load_dwordx4 %0, %1, off" : "=&v"(Q) : "v"(pg_));    \
}

    uint4 Q0, Q1, Q2, Q3, Q4, Q5, Q6, Q7, Q8, Q9, Qa, Qb;
    ISSUE(Q0, 0)  ISSUE(Q1, 1)  ISSUE(Q2, 2)  ISSUE(Q3, 3)
    ISSUE(Q4, 4)  ISSUE(Q5, 5)  ISSUE(Q6, 6)  ISSUE(Q7, 7)
    ISSUE(Q8, 8)  ISSUE(Q9, 9)  ISSUE(Qa, 10) ISSUE(Qb, 11)

    float E0 = 0.f, E1 = 0.f, E2 = 0.f, E3 = 0.f,
          E4 = 0.f, E5 = 0.f, E6 = 0.f, E7 = 0.f;
    float ap = (wl == 0) ? 1.0f : 0.f;

    int s = 0;

#define PHASE(Q) {                                                            \
    asm volatile("s_waitcnt vmcnt(11)" ::: "memory");                         \
    __builtin_amdgcn_sched_barrier(0);                                        \
    float w0 = bflo(Q.x), w1 = bfhi(Q.x), w2 = bflo(Q.y), w3 = bfhi(Q.y);     \
    float w4 = bflo(Q.z), w5 = bfhi(Q.z), w6 = bflo(Q.w), w7 = bfhi(Q.w);     \
    ISSUE(Q, s + DEPTH);                                                      \
    float bu = dpp_shr1_f(E7);                                                \
    float A0 = (ap + E0) * w0, A1 = (E0 + E1) * w1;                           \
    float A2 = (E1 + E2) * w2, A3 = (E2 + E3) * w3;                           \
    float A4 = (E3 + E4) * w4, A5 = (E4 + E5) * w5;                           \
    float A6 = (E5 + E6) * w6, A7 = (E6 + E7) * w7;                           \
    E0 = fmaf(bu, w0, A0);                                                    \
    E1 = fmaf(E0, w1, A1);                                                    \
    E2 = fmaf(E1, w2, A2);                                                    \
    E3 = fmaf(E2, w3, A3);                                                    \
    E4 = fmaf(E3, w4, A4);                                                    \
    E5 = fmaf(E4, w5, A5);                                                    \
    E6 = fmaf(E5, w6, A6);                                                    \
    E7 = fmaf(E6, w7, A7);                                                    \
    ap = bu; ++s;                                                             \
}

    for (;;) {
        PHASE(Q0); if (s > smax) break;
        PHASE(Q1); if (s > smax) break;
        PHASE(Q2); if (s > smax) break;
        PHASE(Q3); if (s > smax) break;
        PHASE(Q4); if (s > smax) break;
        PHASE(Q5); if (s > smax) break;
        PHASE(Q6); if (s > smax) break;
        PHASE(Q7); if (s > smax) break;
        PHASE(Q8); if (s > smax) break;
        PHASE(Q9); if (s > smax) break;
        PHASE(Qa); if (s > smax) break;
        PHASE(Qb); if (s > smax) break;
    }
#undef PHASE
#undef ISSUE
    asm volatile("s_waitcnt vmcnt(0)" ::: "memory");

    if (wl == lout) {
        float eo = E0;
        if (qout == 1) eo = E1; if (qout == 2) eo = E2; if (qout == 3) eo = E3;
        if (qout == 4) eo = E4; if (qout == 5) eo = E5; if (qout == 6) eo = E6;
        if (qout == 7) eo = E7;
        float dv = -GLN2 * LOG2F(eo) * (0.5f / (float)L);
        __hip_atomic_store(&dists[b], dv, __ATOMIC_RELEASE, __HIP_MEMORY_SCOPE_AGENT);
    }

    int old = 0;
    if (wl == 0) {
        old = (int)__hip_atomic_fetch_add(ctr, 1u, __ATOMIC_ACQ_REL,
                                          __HIP_MEMORY_SCOPE_AGENT);
    }
    old = __shfl(old, 0);
    if (old == NBAT - 1) {
        const int g = NGK + 1;
        float part = 0.f;
        if (wl < NWK) {
            float dd[STEPW];
            #pragma unroll
            for (int s2 = 0; s2 < STEPW; ++s2)
                dd[s2] = __hip_atomic_load(&dists[wl * STEPW + s2],
                                           __ATOMIC_RELAXED, __HIP_MEMORY_SCOPE_AGENT);
            float sum_lks = 0.f, nnz = 0.f;
            for (int ii = 0; ii < g; ++ii) {
                float mx = 0.f;
                for (int jj = 0; jj < g; ++jj) {
                    float dmg_ij = 0.5f * (dd[ii] + dd[jj]);
                    for (int f = 0; f < NFK; ++f) {
                        float sc = dmg_ij + 1.0f - 0.5f * (dd[ii] + dd[g + f]);
                        sc = fmaxf(sc, 0.f);
                        mx = fmaxf(mx, sc);
                    }
                }
                sum_lks += mx;
                nnz += (mx != 0.f) ? 1.f : 0.f;
            }
            sum_lks *= (float)(g * NFK);
            nnz     *= (float)(g * NFK);
            float lv = sum_lks / (nnz + 1.f);
            float only_pos = 0.f;
            for (int ii = 1; ii < g; ++ii)
                for (int jj = 0; jj < ii; ++jj)
                    only_pos += 0.5f * (dd[ii] + dd[jj]);
            only_pos *= (0.01f / (float)NGK);
            part = lv + only_pos;
        }
        float tot = 0.f;
        #pragma unroll
        for (int w2 = 0; w2 < NWK; ++w2) tot += __shfl(part, w2);
        if (wl == 0) out[0] = tot * (1.0f / (float)NWK);
    }
}

// ---------------- fallback (round-1 proven kernel) if ws is too small ----------------
#define FXSTR 36
__global__ __launch_bounds__(512, 1) void sdtw_fb(
    const float* __restrict__ data, const int* __restrict__ lens,
    float* __restrict__ dists)
{
    __shared__ __align__(16) float LX[NSEQ * FXSTR];
    __shared__ float LSQ[NSEQ];
    __shared__ float RB[3][NSEQ + 2];

    const int b = blockIdx.x;
    const int t = threadIdx.x;
    const float* xb = data + (size_t)b * (NSEQ * FDIM);

    #pragma unroll
    for (int r = 0; r < 8; ++r) {
        int q = r * 512 + t;
        int j = q >> 3, c4 = (q & 7) << 2;
        float4 v = ((const float4*)xb)[q];
        *(float4*)&LX[j * FXSTR + c4] = v;
    }
    for (int idx = t; idx < 3 * (NSEQ + 2); idx += 512) ((float*)RB)[idx] = BIGV;
    __syncthreads();

    const int i = t;
    float4 xi[8];
    float sqi = 0.f;
    {
        const float* src = &LX[i * FXSTR];
        #pragma unroll
        for (int c = 0; c < 8; ++c) {
            float4 v = *(const float4*)&src[c * 4];
            xi[c] = v;
            sqi += v.x * v.x + v.y * v.y + v.z * v.z + v.w * v.w;
        }
        LSQ[i] = sqi;
    }
    int L = lens[b];
    L = L < 1 ? 1 : (L > NSEQ ? NSEQ : L);
    __syncthreads();

    float lastR = 0.0f;
    if (i == 0) {
        float dot = 0.f;
        #pragma unroll
        for (int c = 0; c < 8; ++c) {
            float4 v = xi[c];
            dot += v.x * v.x + v.y * v.y + v.z * v.z + v.w * v.w;
        }
        float d00 = sqi + sqi - 2.f * dot;
        lastR = d00;
        RB[0][1] = d00;
    }
    __syncthreads();

    float* b0 = RB[1]; float* b1 = RB[0]; float* b2 = RB[2];
    const int kend = 2 * L - 2;
    for (int k = 1; k <= kend; ++k) {
        int j = k - i;
        if (j >= 0 && j < L && i < L) {
            const float* xj = &LX[j * FXSTR];
            float d0 = 0.f, d1 = 0.f, d2 = 0.f, d3 = 0.f;
            #pragma unroll
            for (int c = 0; c < 8; ++c) {
                float4 v = *(const float4*)&xj[c * 4];
                d0 = fmaf(v.x, xi[c].x, d0);
                d1 = fmaf(v.y, xi[c].y, d1);
                d2 = fmaf(v.z, xi[c].z, d2);
                d3 = fmaf(v.w, xi[c].w, d3);
            }
            float dot = (d0 + d1) + (d2 + d3);
            float Dij = sqi + LSQ[j] - 2.f * dot;
            float a = b2[i], bb = b1[i], cc = b1[i + 1];
            float m = fminf(fminf(a, bb), cc);
            float e = EXP2F((m - a) * INVGL) + EXP2F((m - bb) * INVGL)
                    + EXP2F((m - cc) * INVGL);
            float r = Dij + m - GLN2 * LOG2F(e);
            b0[i + 1] = r;
            lastR = r;
        }
        __syncthreads();
        float* tmp = b2; b2 = b1; b1 = b0; b0 = tmp;
    }
    if (i == L - 1) dists[b] = lastR / (2.0f * (float)L);
}

__global__ __launch_bounds__(64) void finalize_kernel(
    const float* __restrict__ dists, float* __restrict__ out)
{
    __shared__ float acc[NWK];
    const int t = threadIdx.x;
    const int g = NGK + 1;
    if (t < NWK) {
        float dd[STEPW];
        #pragma unroll
        for (int s = 0; s < STEPW; ++s) dd[s] = dists[t * STEPW + s];

        float sum_lks = 0.f, nnz = 0.f;
        for (int ii = 0; ii < g; ++ii) {
            float mx = 0.f;
            for (int jj = 0; jj < g; ++jj) {
                float dmg_ij = 0.5f * (dd[ii] + dd[jj]);
                for (int f = 0; f < NFK; ++f) {
                    float s = dmg_ij + 1.0f - 0.5f * (dd[ii] + dd[g + f]);
                    s = fmaxf(s, 0.f);
                    mx = fmaxf(mx, s);
                }
            }
            sum_lks += mx;
            nnz += (mx != 0.f) ? 1.f : 0.f;
        }
        sum_lks *= (float)(g * NFK);
        nnz     *= (float)(g * NFK);
        float lv = sum_lks / (nnz + 1.f);

        float only_pos = 0.f;
        for (int ii = 1; ii < g; ++ii)
            for (int jj = 0; jj < ii; ++jj)
                only_pos += 0.5f * (dd[ii] + dd[jj]);
        only_pos *= (0.01f / (float)NGK);

        acc[t] = lv + only_pos;
    }
    __syncthreads();
    if (t == 0) {
        float s = 0.f;
        #pragma unroll
        for (int w = 0; w < NWK; ++w) s += acc[w];
        out[0] = s * (1.0f / (float)NWK);
    }
}

extern "C" void kernel_launch(void* const* d_in, const int* in_sizes, int n_in,
                              void* d_out, int out_size, void* d_ws, size_t ws_size,
                              hipStream_t stream)
{
    const float* data = (const float*)d_in[0];   // (128, 512, 32) f32
    const int*   lens = (const int*)d_in[1];     // (128,) i32
    float* out   = (float*)d_out;
    float* dists = (float*)d_ws;                 // 128 f32 at offset 0
    uint32_t* ctr = (uint32_t*)((char*)d_ws + 512);

    const size_t OFF_XBF = 1024;
    const size_t OFF_SQ  = OFF_XBF + (size_t)NBAT * NSEQ * FDIM * 2;   // +4 MB
    const size_t OFF_WSK = OFF_SQ  + (size_t)NBAT * NSEQ * 4;          // +256 KB
    const size_t NEED2   = OFF_WSK + (size_t)NBAT * NR2 * 1024 * 2;    // ~88 MB
    const size_t NEED1   = OFF_WSK + (size_t)NBAT * SROWS * NSEQ * 2;  // ~80 MB

    if (ws_size >= NEED2) {
        uint16_t* xbf = (uint16_t*)((char*)d_ws + OFF_XBF);
        float*    sq  = (float*)((char*)d_ws + OFF_SQ);
        uint16_t* wsk = (uint16_t*)((char*)d_ws + OFF_WSK);
        hipMemsetAsync(ctr, 0, 4, stream);
        prep_kernel<<<NBAT, 256, 0, stream>>>(data, xbf, sq);
        dgen2_kernel<<<dim3(32, NBAT), 256, 0, stream>>>(xbf, sq, lens, wsk);
        dp2_kernel<<<NBAT, 64, 0, stream>>>(wsk, lens, dists, ctr, out);
    } else if (ws_size >= NEED1) {
        uint16_t* xbf = (uint16_t*)((char*)d_ws + OFF_XBF);
        float*    sq  = (float*)((char*)d_ws + OFF_SQ);
        uint16_t* wsk = (uint16_t*)((char*)d_ws + OFF_WSK);
        hipMemsetAsync(ctr, 0, 4, stream);
        prep_kernel<<<NBAT, 256, 0, stream>>>(data, xbf, sq);
        dgen_kernel<<<dim3(32, NBAT), 256, 0, stream>>>(xbf, sq, lens, wsk);
        dp_kernel<<<NBAT, 64, 0, stream>>>(wsk, lens, dists, ctr, out);
    } else {
        sdtw_fb<<<NBAT, 512, 0, stream>>>(data, lens, dists);
        finalize_kernel<<<1, 64, 0, stream>>>(dists, out);
    }
}

// Round 11
// 79.049 us; speedup vs baseline: 2.1642x; 1.0483x over previous
//
#include <hip/hip_runtime.h>
#include <stdint.h>

#define NGK   5
#define NFK   10
#define NWK   8
#define STEPW 16      // NG + NF + 1
#define NSEQ  512
#define FDIM  32
#define NBAT  128
#define SROWS 576     // old-layout skewed rows (middle path)
#define DEPTH 12      // middle-path dp ring depth
#define NR2   319     // dstep rows: max S_out = (511+126)/2 = 318
#define BIGV  1000000000.0f

#define INVGL 0.28853900817779268f   // 1/(gamma*ln2)
#define GLN2  3.4657359027997265f    // gamma*ln2

#define EXP2F(x) __builtin_amdgcn_exp2f(x)
#define LOG2F(x) __builtin_amdgcn_logf(x)   // v_log_f32 = log2 (validated r1-r10)

typedef short bf16x8 __attribute__((ext_vector_type(8)));
typedef float f32x4  __attribute__((ext_vector_type(4)));
union U32F { uint32_t u; float f; };

__device__ __forceinline__ uint32_t f2bf(float f) {  // f32 -> bf16 RNE
    U32F c; c.f = f;
    return (c.u + 0x7FFFu + ((c.u >> 16) & 1u)) >> 16;
}
__device__ __forceinline__ float bflo(uint32_t u) { U32F c; c.u = u << 16; return c.f; }
__device__ __forceinline__ float bfhi(uint32_t u) { U32F c; c.u = u & 0xFFFF0000u; return c.f; }

// lane n <- lane n-1 (DPP wave_shr:1 = 0x138); lane 0 -> 0 (= E-domain boundary).
__device__ __forceinline__ float dpp_shr1_f(float v) {
    U32F c; c.f = v;
    c.u = (uint32_t)__builtin_amdgcn_update_dpp(0, (int)c.u, 0x138, 0xF, 0xF, true);
    return c.f;
}

// ---------- kernel 0: stage x -> bf16 rows (64 B) + row norms; zero ctr ----------
__global__ __launch_bounds__(256, 1) void prep_kernel(
    const float* __restrict__ data, uint16_t* __restrict__ xbf,
    float* __restrict__ sq, uint32_t* __restrict__ ctr)
{
    __shared__ uint32_t LB[NSEQ * 16];   // 32 KB bf16-pair rows
    const int b = blockIdx.x;
    const int t = threadIdx.x;
    if (b == 0 && t == 0)
        __hip_atomic_store(ctr, 0u, __ATOMIC_RELEASE, __HIP_MEMORY_SCOPE_AGENT);
    const float4* xb4 = (const float4*)(data + (size_t)b * (NSEQ * FDIM));
    uint2* xg = (uint2*)(xbf + (size_t)b * (NSEQ * FDIM));

    #pragma unroll
    for (int it = 0; it < 16; ++it) {
        int q = it * 256 + t;            // float4 index, 4096 total
        float4 v = xb4[q];
        uint32_t u0 = f2bf(v.x) | (f2bf(v.y) << 16);
        uint32_t u1 = f2bf(v.z) | (f2bf(v.w) << 16);
        LB[q * 2] = u0; LB[q * 2 + 1] = u1;
        uint2 st; st.x = u0; st.y = u1;
        xg[q] = st;
    }
    __syncthreads();
    #pragma unroll
    for (int rr = 0; rr < 2; ++rr) {
        int r = t + rr * 256;
        float acc = 0.f;
        #pragma unroll
        for (int c = 0; c < 16; ++c) {
            uint32_t u = LB[r * 16 + c];
            float lo = bflo(u), hi = bfhi(u);
            acc = fmaf(lo, lo, acc);
            acc = fmaf(hi, hi, acc);
        }
        sq[(size_t)b * NSEQ + r] = acc;
    }
}

// ================= double-step W layout (validated r10) =================
// W2[b][S][l][sub][8] bf16: cell (i,j) -> l=i>>3, q=i&7, c=j+2l, S=c>>1, sub=c&1.
__global__ __launch_bounds__(256, 1) void dgen2_kernel(
    const uint16_t* __restrict__ xbf, const float* __restrict__ sq,
    const int* __restrict__ lens, uint16_t* __restrict__ wsk)
{
    const int tj = blockIdx.x, b = blockIdx.y;
    int L = lens[b]; L = L < 1 ? 1 : (L > NSEQ ? NSEQ : L);
    const int lout = (L - 1) >> 3;
    const int maxS = ((L - 1) + 2 * lout) >> 1;          // = S_out
    if (tj * 16 > 2 * maxS + 1) return;

    const int t = threadIdx.x;
    const int w = t >> 6, lane = t & 63, rl = lane & 15, kq = lane >> 4, rr0 = kq * 4;
    const int j = tj * 16 + rl;

    const short* xb  = (const short*)(xbf + (size_t)b * (NSEQ * FDIM));
    const float* sqb = sq + (size_t)b * NSEQ;
    uint16_t* wb = wsk + (size_t)b * (NR2 * 1024);

    bf16x8 bfrag = *(const bf16x8*)(xb + j * FDIM + kq * 8);   // validated B-frag
    float sqJ = sqb[j];
    const bool jok = j < L;
    const int q0 = rr0 & 7;                // 0 or 4
    const int ladd = rr0 >> 3;             // 0 or 1

    for (int it = 0; it < 8; ++it) {
        int ti = w * 8 + it;
        if (tj * 16 + 4 * ti > 2 * maxS + 1) break;      // wave-uniform skip
        bf16x8 afrag = *(const bf16x8*)(xb + (ti * 16 + rl) * FDIM + kq * 8);
        f32x4 c = {0.f, 0.f, 0.f, 0.f};
        c = __builtin_amdgcn_mfma_f32_16x16x32_bf16(afrag, bfrag, c, 0, 0, 0);
        f32x4 s4 = *(const f32x4*)(sqb + ti * 16 + rr0);
        float wv[4];
        #pragma unroll
        for (int q2 = 0; q2 < 4; ++q2) {
            int i = ti * 16 + rr0 + q2;
            float dv = s4[q2] + sqJ - 2.f * c[q2];
            float e = EXP2F(-INVGL * dv);
            wv[q2] = (jok && (i < L)) ? e : 0.f;
        }
        int l  = ti * 2 + ladd;
        int cc = j + 2 * l;
        int S  = cc >> 1, sub = cc & 1;
        if (S <= maxS) {
            uint2 st;
            st.x = f2bf(wv[0]) | (f2bf(wv[1]) << 16);
            st.y = f2bf(wv[2]) | (f2bf(wv[3]) << 16);
            *(uint2*)(wb + (size_t)S * 1024 + l * 16 + sub * 8 + q0) = st;
        }
    }
}

// dp2: 2 columns per dstep, cross-step software-pipelined unpack:
// phase = {reissue slot, vmcnt(14), sched_barrier, unpack row s+1 (other W set),
// FMA chains for row s (pre-unpacked)} -> unpack issue fills chain bubbles.
__global__ __launch_bounds__(64, 1) void dp2_kernel(
    const uint16_t* __restrict__ wsk, const int* __restrict__ lens,
    float* __restrict__ dists, uint32_t* __restrict__ ctr,
    float* __restrict__ out)
{
    const int b = blockIdx.x, wl = threadIdx.x;
    const uint16_t* wb = wsk + (size_t)b * (NR2 * 1024) + wl * 16;
    int L = lens[b]; L = L < 1 ? 1 : (L > NSEQ ? NSEQ : L);
    const int lout = (L - 1) >> 3, qout = (L - 1) & 7;
    const int cout = (L - 1) + 2 * lout;
    const int S_out = cout >> 1;

#define ISSUE2(QA, QB, row) {                                                 \
    int gl_ = (row); if (gl_ > NR2 - 1) gl_ = NR2 - 1;                        \
    const uint16_t* pg_ = wb + (size_t)gl_ * 1024;                            \
    asm volatile("global_load_dwordx4 %0, %2, off\n\t"                        \
                 "global_load_dwordx4 %1, %2, off offset:16"                  \
                 : "=&v"(QA), "=&v"(QB) : "v"(pg_));                          \
}

    uint4 A0r, B0r, A1r, B1r, A2r, B2r, A3r, B3r,
          A4r, B4r, A5r, B5r, A6r, B6r, A7r, B7r;
    ISSUE2(A0r, B0r, 0) ISSUE2(A1r, B1r, 1) ISSUE2(A2r, B2r, 2) ISSUE2(A3r, B3r, 3)
    ISSUE2(A4r, B4r, 4) ISSUE2(A5r, B5r, 5) ISSUE2(A6r, B6r, 6) ISSUE2(A7r, B7r, 7)

    float E0 = 0.f, E1 = 0.f, E2 = 0.f, E3 = 0.f,
          E4 = 0.f, E5 = 0.f, E6 = 0.f, E7 = 0.f;     // colB state
    float f0 = 0.f, f1 = 0.f, f2 = 0.f, f3 = 0.f,
          f4 = 0.f, f5 = 0.f, f6 = 0.f, f7 = 0.f;     // colA state
    float ap  = (wl == 0) ? 1.0f : 0.f;  // diag pred of (8wl, j0)
    float f7p = 0.f;                     // own F7 of prev dstep

    // W double-buffer (constant-indexed arrays -> registers)
    float wxa[8], wxb[8], wya[8], wyb[8];

#define UNPACK(WA, WB, QA, QB) {                                              \
    WA[0] = bflo(QA.x); WA[1] = bfhi(QA.x); WA[2] = bflo(QA.y); WA[3] = bfhi(QA.y); \
    WA[4] = bflo(QA.z); WA[5] = bfhi(QA.z); WA[6] = bflo(QA.w); WA[7] = bfhi(QA.w); \
    WB[0] = bflo(QB.x); WB[1] = bfhi(QB.x); WB[2] = bflo(QB.y); WB[3] = bfhi(QB.y); \
    WB[4] = bflo(QB.z); WB[5] = bfhi(QB.z); WB[6] = bflo(QB.w); WB[7] = bfhi(QB.w); \
}

#define CHAIN(WA, WB) {                                                       \
    float buA = dpp_shr1_f(f7p);                                              \
    float buB = dpp_shr1_f(E7);                                               \
    float a0 = (ap + E0) * WA[0], a1 = (E0 + E1) * WA[1];                     \
    float a2 = (E1 + E2) * WA[2], a3 = (E2 + E3) * WA[3];                     \
    float a4 = (E3 + E4) * WA[4], a5 = (E4 + E5) * WA[5];                     \
    float a6 = (E5 + E6) * WA[6], a7 = (E6 + E7) * WA[7];                     \
    f0 = fmaf(buA, WA[0], a0);                                                \
    f1 = fmaf(f0, WA[1], a1);                                                 \
    f2 = fmaf(f1, WA[2], a2);                                                 \
    f3 = fmaf(f2, WA[3], a3);                                                 \
    f4 = fmaf(f3, WA[4], a4);                                                 \
    f5 = fmaf(f4, WA[5], a5);                                                 \
    f6 = fmaf(f5, WA[6], a6);                                                 \
    f7 = fmaf(f6, WA[7], a7);                                                 \
    float b0 = (buA + f0) * WB[0], b1 = (f0 + f1) * WB[1];                    \
    float b2 = (f1 + f2) * WB[2], b3 = (f2 + f3) * WB[3];                     \
    float b4 = (f3 + f4) * WB[4], b5 = (f4 + f5) * WB[5];                     \
    float b6 = (f5 + f6) * WB[6], b7 = (f6 + f7) * WB[7];                     \
    E0 = fmaf(buB, WB[0], b0);                                                \
    E1 = fmaf(E0, WB[1], b1);                                                 \
    E2 = fmaf(E1, WB[2], b2);                                                 \
    E3 = fmaf(E2, WB[3], b3);                                                 \
    E4 = fmaf(E3, WB[4], b4);                                                 \
    E5 = fmaf(E4, WB[5], b5);                                                 \
    E6 = fmaf(E5, WB[6], b6);                                                 \
    E7 = fmaf(E6, WB[7], b7);                                                 \
    ap = buB; f7p = f7;                                                       \
}

// phase: reissue freed slot (row s+8); wait row s+1; unpack s+1 into WU;
// chain row s from WC (unpack & chain interleave -- no barrier between them)
#define PH(QAr, QBr, QAu, QBu, WUA, WUB, WCA, WCB) {                          \
    ISSUE2(QAr, QBr, s + 8);                                                  \
    asm volatile("s_waitcnt vmcnt(14)" ::: "memory");                         \
    __builtin_amdgcn_sched_barrier(0);                                        \
    UNPACK(WUA, WUB, QAu, QBu);                                               \
    CHAIN(WCA, WCB);                                                          \
    ++s;                                                                      \
}

    int s = 0;
    // prologue: row 0 landed after vmcnt(14); unpack into wx
    asm volatile("s_waitcnt vmcnt(14)" ::: "memory");
    __builtin_amdgcn_sched_barrier(0);
    UNPACK(wxa, wxb, A0r, B0r);

    for (;;) {
        PH(A0r, B0r, A1r, B1r, wya, wyb, wxa, wxb); if (s > S_out) break;
        PH(A1r, B1r, A2r, B2r, wxa, wxb, wya, wyb); if (s > S_out) break;
        PH(A2r, B2r, A3r, B3r, wya, wyb, wxa, wxb); if (s > S_out) break;
        PH(A3r, B3r, A4r, B4r, wxa, wxb, wya, wyb); if (s > S_out) break;
        PH(A4r, B4r, A5r, B5r, wya, wyb, wxa, wxb); if (s > S_out) break;
        PH(A5r, B5r, A6r, B6r, wxa, wxb, wya, wyb); if (s > S_out) break;
        PH(A6r, B6r, A7r, B7r, wya, wyb, wxa, wxb); if (s > S_out) break;
        PH(A7r, B7r, A0r, B0r, wxa, wxb, wya, wyb); if (s > S_out) break;
    }
#undef PH
#undef CHAIN
#undef UNPACK
#undef ISSUE2
    asm volatile("s_waitcnt vmcnt(0)" ::: "memory");   // drain before exit

    if (wl == lout) {
        float eo;
        if ((cout & 1) == 0) {           // output col = last colA -> f regs
            eo = f0;
            if (qout == 1) eo = f1; if (qout == 2) eo = f2; if (qout == 3) eo = f3;
            if (qout == 4) eo = f4; if (qout == 5) eo = f5; if (qout == 6) eo = f6;
            if (qout == 7) eo = f7;
        } else {                         // output col = last colB -> E regs
            eo = E0;
            if (qout == 1) eo = E1; if (qout == 2) eo = E2; if (qout == 3) eo = E3;
            if (qout == 4) eo = E4; if (qout == 5) eo = E5; if (qout == 6) eo = E6;
            if (qout == 7) eo = E7;
        }
        float dv = -GLN2 * LOG2F(eo) * (0.5f / (float)L);
        __hip_atomic_store(&dists[b], dv, __ATOMIC_RELEASE, __HIP_MEMORY_SCOPE_AGENT);
    }

    // ---- fused finalize: last-arriving block reduces the 128 dists ----
    int old = 0;
    if (wl == 0) {
        old = (int)__hip_atomic_fetch_add(ctr, 1u, __ATOMIC_ACQ_REL,
                                          __HIP_MEMORY_SCOPE_AGENT);
    }
    old = __shfl(old, 0);
    if (old == NBAT - 1) {
        const int g = NGK + 1;  // 6
        float part = 0.f;
        if (wl < NWK) {
            float dd[STEPW];
            #pragma unroll
            for (int s2 = 0; s2 < STEPW; ++s2)
                dd[s2] = __hip_atomic_load(&dists[wl * STEPW + s2],
                                           __ATOMIC_RELAXED, __HIP_MEMORY_SCOPE_AGENT);
            float sum_lks = 0.f, nnz = 0.f;
            for (int ii = 0; ii < g; ++ii) {
                float mx = 0.f;
                for (int jj = 0; jj < g; ++jj) {
                    float dmg_ij = 0.5f * (dd[ii] + dd[jj]);
                    for (int f = 0; f < NFK; ++f) {
                        float sc = dmg_ij + 1.0f - 0.5f * (dd[ii] + dd[g + f]);
                        sc = fmaxf(sc, 0.f);
                        mx = fmaxf(mx, sc);
                    }
                }
                sum_lks += mx;
                nnz += (mx != 0.f) ? 1.f : 0.f;
            }
            sum_lks *= (float)(g * NFK);
            nnz     *= (float)(g * NFK);
            float lv = sum_lks / (nnz + 1.f);
            float only_pos = 0.f;
            for (int ii = 1; ii < g; ++ii)
                for (int jj = 0; jj < ii; ++jj)
                    only_pos += 0.5f * (dd[ii] + dd[jj]);
            only_pos *= (0.01f / (float)NGK);
            part = lv + only_pos;
        }
        float tot = 0.f;
        #pragma unroll
        for (int w2 = 0; w2 < NWK; ++w2) tot += __shfl(part, w2);
        if (wl == 0) out[0] = tot * (1.0f / (float)NWK);
    }
}

// ================= MIDDLE PATH: r9 validated single-step =================
__global__ __launch_bounds__(256, 1) void dgen_kernel(
    const uint16_t* __restrict__ xbf, const float* __restrict__ sq,
    const int* __restrict__ lens, uint16_t* __restrict__ wsk)
{
    const int tj = blockIdx.x, b = blockIdx.y;
    int L = lens[b]; L = L < 1 ? 1 : (L > NSEQ ? NSEQ : L);
    const int smax = (L - 1) + ((L - 1) >> 3);
    int maxrow = smax + 8; if (maxrow > SROWS - 1) maxrow = SROWS - 1;
    if (tj * 16 > maxrow) return;

    const int t = threadIdx.x;
    const int w = t >> 6, lane = t & 63, rl = lane & 15, kq = lane >> 4, rr0 = kq * 4;
    const int j = tj * 16 + rl;

    const short* xb  = (const short*)(xbf + (size_t)b * (NSEQ * FDIM));
    const float* sqb = sq + (size_t)b * NSEQ;
    uint16_t* wb = wsk + (size_t)b * (SROWS * NSEQ);

    bf16x8 bfrag = *(const bf16x8*)(xb + j * FDIM + kq * 8);
    float sqJ = sqb[j];
    const bool jok = j < L;

    for (int it = 0; it < 8; ++it) {
        int ti = w * 8 + it;
        if (tj * 16 + ti * 2 > maxrow) break;
        bf16x8 afrag = *(const bf16x8*)(xb + (ti * 16 + rl) * FDIM + kq * 8);
        f32x4 c = {0.f, 0.f, 0.f, 0.f};
        c = __builtin_amdgcn_mfma_f32_16x16x32_bf16(afrag, bfrag, c, 0, 0, 0);
        f32x4 s4 = *(const f32x4*)(sqb + ti * 16 + rr0);
        float wv[4];
        #pragma unroll
        for (int q2 = 0; q2 < 4; ++q2) {
            int i = ti * 16 + rr0 + q2;
            float dv = s4[q2] + sqJ - 2.f * c[q2];
            float e = EXP2F(-INVGL * dv);
            wv[q2] = (jok && (i < L)) ? e : 0.f;
        }
        int sr = j + ti * 2 + (rr0 >> 3);
        uint2 st;
        st.x = f2bf(wv[0]) | (f2bf(wv[1]) << 16);
        st.y = f2bf(wv[2]) | (f2bf(wv[3]) << 16);
        *(uint2*)(wb + (size_t)sr * NSEQ + ti * 16 + rr0) = st;
    }
}

__global__ __launch_bounds__(64, 1) void dp_kernel(
    const uint16_t* __restrict__ wsk, const int* __restrict__ lens,
    float* __restrict__ dists, uint32_t* __restrict__ ctr,
    float* __restrict__ out)
{
    const int b = blockIdx.x, wl = threadIdx.x;
    const uint16_t* wb = wsk + (size_t)b * (SROWS * NSEQ) + wl * 8;
    int L = lens[b]; L = L < 1 ? 1 : (L > NSEQ ? NSEQ : L);
    const int lout = (L - 1) >> 3, qout = (L - 1) & 7, smax = (L - 1) + lout;

#define ISSUE(Q, row) {                                                       \
    int gl_ = (row); if (gl_ > SROWS - 1) gl_ = SROWS - 1;                    \
    const uint16_t* pg_ = wb + (size_t)gl_ * NSEQ;                            \
    asm volatile("global_load_dwordx4 %0, %1, off" : "=&v"(Q) : "v"(pg_));    \
}

    uint4 Q0, Q1, Q2, Q3, Q4, Q5, Q6, Q7, Q8, Q9, Qa, Qb;
    ISSUE(Q0, 0)  ISSUE(Q1, 1)  ISSUE(Q2, 2)  ISSUE(Q3, 3)
    ISSUE(Q4, 4)  ISSUE(Q5, 5)  ISSUE(Q6, 6)  ISSUE(Q7, 7)
    ISSUE(Q8, 8)  ISSUE(Q9, 9)  ISSUE(Qa, 10) ISSUE(Qb, 11)

    float E0 = 0.f, E1 = 0.f, E2 = 0.f, E3 = 0.f,
          E4 = 0.f, E5 = 0.f, E6 = 0.f, E7 = 0.f;
    float ap = (wl == 0) ? 1.0f : 0.f;

    int s = 0;

#define PHASE(Q) {                                                            \
    asm volatile("s_waitcnt vmcnt(11)" ::: "memory");                         \
    __builtin_amdgcn_sched_barrier(0);                                        \
    float w0 = bflo(Q.x), w1 = bfhi(Q.x), w2 = bflo(Q.y), w3 = bfhi(Q.y);     \
    float w4 = bflo(Q.z), w5 = bfhi(Q.z), w6 = bflo(Q.w), w7 = bfhi(Q.w);     \
    ISSUE(Q, s + DEPTH);                                                      \
    float bu = dpp_shr1_f(E7);                                                \
    float A0 = (ap + E0) * w0, A1 = (E0 + E1) * w1;                           \
    float A2 = (E1 + E2) * w2, A3 = (E2 + E3) * w3;                           \
    float A4 = (E3 + E4) * w4, A5 = (E4 + E5) * w5;                           \
    float A6 = (E5 + E6) * w6, A7 = (E6 + E7) * w7;                           \
    E0 = fmaf(bu, w0, A0);                                                    \
    E1 = fmaf(E0, w1, A1);                                                    \
    E2 = fmaf(E1, w2, A2);                                                    \
    E3 = fmaf(E2, w3, A3);                                                    \
    E4 = fmaf(E3, w4, A4);                                                    \
    E5 = fmaf(E4, w5, A5);                                                    \
    E6 = fmaf(E5, w6, A6);                                                    \
    E7 = fmaf(E6, w7, A7);                                                    \
    ap = bu; ++s;                                                             \
}

    for (;;) {
        PHASE(Q0); if (s > smax) break;
        PHASE(Q1); if (s > smax) break;
        PHASE(Q2); if (s > smax) break;
        PHASE(Q3); if (s > smax) break;
        PHASE(Q4); if (s > smax) break;
        PHASE(Q5); if (s > smax) break;
        PHASE(Q6); if (s > smax) break;
        PHASE(Q7); if (s > smax) break;
        PHASE(Q8); if (s > smax) break;
        PHASE(Q9); if (s > smax) break;
        PHASE(Qa); if (s > smax) break;
        PHASE(Qb); if (s > smax) break;
    }
#undef PHASE
#undef ISSUE
    asm volatile("s_waitcnt vmcnt(0)" ::: "memory");

    if (wl == lout) {
        float eo = E0;
        if (qout == 1) eo = E1; if (qout == 2) eo = E2; if (qout == 3) eo = E3;
        if (qout == 4) eo = E4; if (qout == 5) eo = E5; if (qout == 6) eo = E6;
        if (qout == 7) eo = E7;
        float dv = -GLN2 * LOG2F(eo) * (0.5f / (float)L);
        __hip_atomic_store(&dists[b], dv, __ATOMIC_RELEASE, __HIP_MEMORY_SCOPE_AGENT);
    }

    int old = 0;
    if (wl == 0) {
        old = (int)__hip_atomic_fetch_add(ctr, 1u, __ATOMIC_ACQ_REL,
                                          __HIP_MEMORY_SCOPE_AGENT);
    }
    old = __shfl(old, 0);
    if (old == NBAT - 1) {
        const int g = NGK + 1;
        float part = 0.f;
        if (wl < NWK) {
            float dd[STEPW];
            #pragma unroll
            for (int s2 = 0; s2 < STEPW; ++s2)
                dd[s2] = __hip_atomic_load(&dists[wl * STEPW + s2],
                                           __ATOMIC_RELAXED, __HIP_MEMORY_SCOPE_AGENT);
            float sum_lks = 0.f, nnz = 0.f;
            for (int ii = 0; ii < g; ++ii) {
                float mx = 0.f;
                for (int jj = 0; jj < g; ++jj) {
                    float dmg_ij = 0.5f * (dd[ii] + dd[jj]);
                    for (int f = 0; f < NFK; ++f) {
                        float sc = dmg_ij + 1.0f - 0.5f * (dd[ii] + dd[g + f]);
                        sc = fmaxf(sc, 0.f);
                        mx = fmaxf(mx, sc);
                    }
                }
                sum_lks += mx;
                nnz += (mx != 0.f) ? 1.f : 0.f;
            }
            sum_lks *= (float)(g * NFK);
            nnz     *= (float)(g * NFK);
            float lv = sum_lks / (nnz + 1.f);
            float only_pos = 0.f;
            for (int ii = 1; ii < g; ++ii)
                for (int jj = 0; jj < ii; ++jj)
                    only_pos += 0.5f * (dd[ii] + dd[jj]);
            only_pos *= (0.01f / (float)NGK);
            part = lv + only_pos;
        }
        float tot = 0.f;
        #pragma unroll
        for (int w2 = 0; w2 < NWK; ++w2) tot += __shfl(part, w2);
        if (wl == 0) out[0] = tot * (1.0f / (float)NWK);
    }
}

// ---------------- fallback (round-1 proven kernel) if ws is too small ----------------
#define FXSTR 36
__global__ __launch_bounds__(512, 1) void sdtw_fb(
    const float* __restrict__ data, const int* __restrict__ lens,
    float* __restrict__ dists)
{
    __shared__ __align__(16) float LX[NSEQ * FXSTR];
    __shared__ float LSQ[NSEQ];
    __shared__ float RB[3][NSEQ + 2];

    const int b = blockIdx.x;
    const int t = threadIdx.x;
    const float* xb = data + (size_t)b * (NSEQ * FDIM);

    #pragma unroll
    for (int r = 0; r < 8; ++r) {
        int q = r * 512 + t;
        int j = q >> 3, c4 = (q & 7) << 2;
        float4 v = ((const float4*)xb)[q];
        *(float4*)&LX[j * FXSTR + c4] = v;
    }
    for (int idx = t; idx < 3 * (NSEQ + 2); idx += 512) ((float*)RB)[idx] = BIGV;
    __syncthreads();

    const int i = t;
    float4 xi[8];
    float sqi = 0.f;
    {
        const float* src = &LX[i * FXSTR];
        #pragma unroll
        for (int c = 0; c < 8; ++c) {
            float4 v = *(const float4*)&src[c * 4];
            xi[c] = v;
            sqi += v.x * v.x + v.y * v.y + v.z * v.z + v.w * v.w;
        }
        LSQ[i] = sqi;
    }
    int L = lens[b];
    L = L < 1 ? 1 : (L > NSEQ ? NSEQ : L);
    __syncthreads();

    float lastR = 0.0f;
    if (i == 0) {
        float dot = 0.f;
        #pragma unroll
        for (int c = 0; c < 8; ++c) {
            float4 v = xi[c];
            dot += v.x * v.x + v.y * v.y + v.z * v.z + v.w * v.w;
        }
        float d00 = sqi + sqi - 2.f * dot;
        lastR = d00;
        RB[0][1] = d00;
    }
    __syncthreads();

    float* b0 = RB[1]; float* b1 = RB[0]; float* b2 = RB[2];
    const int kend = 2 * L - 2;
    for (int k = 1; k <= kend; ++k) {
        int j = k - i;
        if (j >= 0 && j < L && i < L) {
            const float* xj = &LX[j * FXSTR];
            float d0 = 0.f, d1 = 0.f, d2 = 0.f, d3 = 0.f;
            #pragma unroll
            for (int c = 0; c < 8; ++c) {
                float4 v = *(const float4*)&xj[c * 4];
                d0 = fmaf(v.x, xi[c].x, d0);
                d1 = fmaf(v.y, xi[c].y, d1);
                d2 = fmaf(v.z, xi[c].z, d2);
                d3 = fmaf(v.w, xi[c].w, d3);
            }
            float dot = (d0 + d1) + (d2 + d3);
            float Dij = sqi + LSQ[j] - 2.f * dot;
            float a = b2[i], bb = b1[i], cc = b1[i + 1];
            float m = fminf(fminf(a, bb), cc);
            float e = EXP2F((m - a) * INVGL) + EXP2F((m - bb) * INVGL)
                    + EXP2F((m - cc) * INVGL);
            float r = Dij + m - GLN2 * LOG2F(e);
            b0[i + 1] = r;
            lastR = r;
        }
        __syncthreads();
        float* tmp = b2; b2 = b1; b1 = b0; b0 = tmp;
    }
    if (i == L - 1) dists[b] = lastR / (2.0f * (float)L);
}

__global__ __launch_bounds__(64) void finalize_kernel(
    const float* __restrict__ dists, float* __restrict__ out)
{
    __shared__ float acc[NWK];
    const int t = threadIdx.x;
    const int g = NGK + 1;
    if (t < NWK) {
        float dd[STEPW];
        #pragma unroll
        for (int s = 0; s < STEPW; ++s) dd[s] = dists[t * STEPW + s];

        float sum_lks = 0.f, nnz = 0.f;
        for (int ii = 0; ii < g; ++ii) {
            float mx = 0.f;
            for (int jj = 0; jj < g; ++jj) {
                float dmg_ij = 0.5f * (dd[ii] + dd[jj]);
                for (int f = 0; f < NFK; ++f) {
                    float s = dmg_ij + 1.0f - 0.5f * (dd[ii] + dd[g + f]);
                    s = fmaxf(s, 0.f);
                    mx = fmaxf(mx, s);
                }
            }
            sum_lks += mx;
            nnz += (mx != 0.f) ? 1.f : 0.f;
        }
        sum_lks *= (float)(g * NFK);
        nnz     *= (float)(g * NFK);
        float lv = sum_lks / (nnz + 1.f);

        float only_pos = 0.f;
        for (int ii = 1; ii < g; ++ii)
            for (int jj = 0; jj < ii; ++jj)
                only_pos += 0.5f * (dd[ii] + dd[jj]);
        only_pos *= (0.01f / (float)NGK);

        acc[t] = lv + only_pos;
    }
    __syncthreads();
    if (t == 0) {
        float s = 0.f;
        #pragma unroll
        for (int w = 0; w < NWK; ++w) s += acc[w];
        out[0] = s * (1.0f / (float)NWK);
    }
}

extern "C" void kernel_launch(void* const* d_in, const int* in_sizes, int n_in,
                              void* d_out, int out_size, void* d_ws, size_t ws_size,
                              hipStream_t stream)
{
    const float* data = (const float*)d_in[0];   // (128, 512, 32) f32
    const int*   lens = (const int*)d_in[1];     // (128,) i32
    float* out   = (float*)d_out;
    float* dists = (float*)d_ws;                 // 128 f32 at offset 0
    uint32_t* ctr = (uint32_t*)((char*)d_ws + 512);

    const size_t OFF_XBF = 1024;
    const size_t OFF_SQ  = OFF_XBF + (size_t)NBAT * NSEQ * FDIM * 2;   // +4 MB
    const size_t OFF_WSK = OFF_SQ  + (size_t)NBAT * NSEQ * 4;          // +256 KB
    const size_t NEED2   = OFF_WSK + (size_t)NBAT * NR2 * 1024 * 2;    // ~88 MB
    const size_t NEED1   = OFF_WSK + (size_t)NBAT * SROWS * NSEQ * 2;  // ~80 MB

    if (ws_size >= NEED2) {
        uint16_t* xbf = (uint16_t*)((char*)d_ws + OFF_XBF);
        float*    sq  = (float*)((char*)d_ws + OFF_SQ);
        uint16_t* wsk = (uint16_t*)((char*)d_ws + OFF_WSK);
        prep_kernel<<<NBAT, 256, 0, stream>>>(data, xbf, sq, ctr);
        dgen2_kernel<<<dim3(32, NBAT), 256, 0, stream>>>(xbf, sq, lens, wsk);
        dp2_kernel<<<NBAT, 64, 0, stream>>>(wsk, lens, dists, ctr, out);
    } else if (ws_size >= NEED1) {
        uint16_t* xbf = (uint16_t*)((char*)d_ws + OFF_XBF);
        float*    sq  = (float*)((char*)d_ws + OFF_SQ);
        uint16_t* wsk = (uint16_t*)((char*)d_ws + OFF_WSK);
        prep_kernel<<<NBAT, 256, 0, stream>>>(data, xbf, sq, ctr);
        dgen_kernel<<<dim3(32, NBAT), 256, 0, stream>>>(xbf, sq, lens, wsk);
        dp_kernel<<<NBAT, 64, 0, stream>>>(wsk, lens, dists, ctr, out);
    } else {
        sdtw_fb<<<NBAT, 512, 0, stream>>>(data, lens, dists);
        finalize_kernel<<<1, 64, 0, stream>>>(dists, out);
    }
}